// Round 12
// baseline (692.575 us; speedup 1.0000x reference)
//
#include <hip/hip_runtime.h>
#include <cmath>

#define CH 128          // scan chunk length
#define NC 32           // 4096 / CH

typedef __bf16 bf16_t;
typedef __attribute__((ext_vector_type(8))) __bf16 bf16x8;
typedef __attribute__((ext_vector_type(4))) __bf16 bf16x4;
typedef __attribute__((ext_vector_type(4))) float f32x4;

// CK idiom: generic->AS1/AS3 via uintptr for global_load_lds (width 16).
// NOTE (m104): LDS dest must be LINEAR in lane order (base + lane*16);
// any layout permutation must be applied to the GLOBAL source address.
#define GLOAD_LDS16(gp, lp)                                                     \
    __builtin_amdgcn_global_load_lds(                                           \
        (const __attribute__((address_space(1))) unsigned int*)(uintptr_t)(gp), \
        (__attribute__((address_space(3))) unsigned int*)(uintptr_t)(lp),       \
        16, 0, 0)

// ---------------------------------------------------------------------------
// fp32 -> (hi, lo) bf16 split.  4 floats per thread.
// ---------------------------------------------------------------------------
__global__ __launch_bounds__(256) void split_hl(
    const float* __restrict__ in, bf16_t* __restrict__ hi,
    bf16_t* __restrict__ lo, int n4)
{
    const int i = blockIdx.x * 256 + threadIdx.x;
    if (i >= n4) return;
    const float4 v = ((const float4*)in)[i];
    const bf16_t h0 = (bf16_t)v.x, h1 = (bf16_t)v.y,
                 h2 = (bf16_t)v.z, h3 = (bf16_t)v.w;
    bf16x4 hv = {h0, h1, h2, h3};
    bf16x4 lv = {(bf16_t)(v.x - (float)h0), (bf16_t)(v.y - (float)h1),
                 (bf16_t)(v.z - (float)h2), (bf16_t)(v.w - (float)h3)};
    ((bf16x4*)hi)[i] = hv;
    ((bf16x4*)lo)[i] = lv;
}

// ---------------------------------------------------------------------------
// Fused t=0 splits: hidden + in_proj_w.  (dt_proj_w split must wait until
// w1 is dead -- there is no free workspace at t=0.)
// ---------------------------------------------------------------------------
__global__ __launch_bounds__(256) void split2(
    const float* __restrict__ a, bf16_t* __restrict__ ah, bf16_t* __restrict__ al, int n4a,
    const float* __restrict__ b, bf16_t* __restrict__ bh, bf16_t* __restrict__ bl, int n4b)
{
    const int i = blockIdx.x * 256 + threadIdx.x;
    const float* src; bf16_t* hp; bf16_t* lp; int j;
    if (i < n4a)            { src = a; hp = ah; lp = al; j = i; }
    else if (i < n4a + n4b) { src = b; hp = bh; lp = bl; j = i - n4a; }
    else return;

    const float4 v = ((const float4*)src)[j];
    const bf16_t h0 = (bf16_t)v.x, h1 = (bf16_t)v.y,
                 h2 = (bf16_t)v.z, h3 = (bf16_t)v.w;
    bf16x4 hv = {h0, h1, h2, h3};
    bf16x4 lv = {(bf16_t)(v.x - (float)h0), (bf16_t)(v.y - (float)h1),
                 (bf16_t)(v.z - (float)h2), (bf16_t)(v.w - (float)h3)};
    ((bf16x4*)hp)[j] = hv;
    ((bf16x4*)lp)[j] = lv;
}

// ---------------------------------------------------------------------------
// x_proj split-K reduce + dt-slice hi/lo emit.
// ---------------------------------------------------------------------------
__global__ __launch_bounds__(256) void add8_split(
    const float* __restrict__ p, float* __restrict__ o,
    bf16_t* __restrict__ dth, bf16_t* __restrict__ dtl,
    int n4, size_t stride4)
{
    const int i = blockIdx.x * 256 + threadIdx.x;
    if (i >= n4) return;
    float4 s = make_float4(0.f, 0.f, 0.f, 0.f);
#pragma unroll
    for (int k = 0; k < 8; ++k) {
        const float4 v = ((const float4*)p)[(size_t)k * stride4 + i];
        s.x += v.x; s.y += v.y; s.z += v.z; s.w += v.w;
    }
    ((float4*)o)[i] = s;

    const int col4 = i % 24;
    if (col4 < 16) {
        const int row = i / 24;
        const bf16_t h0 = (bf16_t)s.x, h1 = (bf16_t)s.y,
                     h2 = (bf16_t)s.z, h3 = (bf16_t)s.w;
        bf16x4 hv = {h0, h1, h2, h3};
        bf16x4 lv = {(bf16_t)(s.x - (float)h0), (bf16_t)(s.y - (float)h1),
                     (bf16_t)(s.z - (float)h2), (bf16_t)(s.w - (float)h3)};
        ((bf16x4*)dth)[(size_t)row * 16 + col4] = hv;
        ((bf16x4*)dtl)[(size_t)row * 16 + col4] = lv;
    }
}

// ---------------------------------------------------------------------------
// Fused in_proj: blockIdx.y < 16 -> x-half (3-term split precision),
//                blockIdx.y >= 16 -> z-half (1-term bf16, gate-only use).
// 128x128 tile, BK=32, 4 waves, mfma_f32_16x16x32_bf16.
// ---------------------------------------------------------------------------
__global__ __launch_bounds__(256) void in_proj_fused(
    const bf16_t* __restrict__ Ah, const bf16_t* __restrict__ Al,
    const bf16_t* __restrict__ Wh, const bf16_t* __restrict__ Wl,
    float* __restrict__ X, float* __restrict__ Z, int Ktot)
{
    __shared__ __align__(16) bf16_t Ash[128 * 32];
    __shared__ __align__(16) bf16_t Asl[128 * 32];
    __shared__ __align__(16) bf16_t Bsh[128 * 32];
    __shared__ __align__(16) bf16_t Bsl[128 * 32];

    const int tid  = threadIdx.x;
    const int lane = tid & 63;
    const int w    = tid >> 6;
    const int wr   = (w >> 1) * 64;
    const int wc   = (w & 1) * 64;
    const int bm   = blockIdx.x * 128;
    const int by   = blockIdx.y;
    const int l16  = lane & 15;
    const int lhi  = lane >> 4;

    f32x4 acc[4][4];
#pragma unroll
    for (int i = 0; i < 4; ++i)
#pragma unroll
        for (int j = 0; j < 4; ++j)
#pragma unroll
            for (int r = 0; r < 4; ++r) acc[i][j][r] = 0.f;

    const int srow0 = tid >> 2;
    const int sks   = (tid & 3) << 3;
    const int ldsb0 = tid * 16;

    if (by < 16) {
        // ---- x-half: 3-term ----
        const int bn = by * 128;
        for (int k0 = 0; k0 < Ktot; k0 += 32) {
            __syncthreads();
#pragma unroll
            for (int call = 0; call < 2; ++call) {
                const int row = srow0 + call * 64;
                const int wb  = ldsb0 + call * 4096;
                const size_t aoff = (size_t)(bm + row) * Ktot + k0 + sks;
                const size_t boff = (size_t)(bn + row) * Ktot + k0 + sks;
                GLOAD_LDS16(Ah + aoff, (char*)Ash + wb);
                GLOAD_LDS16(Al + aoff, (char*)Asl + wb);
                GLOAD_LDS16(Wh + boff, (char*)Bsh + wb);
                GLOAD_LDS16(Wl + boff, (char*)Bsl + wb);
            }
            __syncthreads();

            bf16x8 ah[4], al[4], bh[4], bl[4];
#pragma unroll
            for (int f = 0; f < 4; ++f) {
                const int ar = (wr + f * 16 + l16) * 32 + lhi * 8;
                const int br = (wc + f * 16 + l16) * 32 + lhi * 8;
                ah[f] = *(const bf16x8*)&Ash[ar];
                al[f] = *(const bf16x8*)&Asl[ar];
                bh[f] = *(const bf16x8*)&Bsh[br];
                bl[f] = *(const bf16x8*)&Bsl[br];
            }
#pragma unroll
            for (int fm = 0; fm < 4; ++fm)
#pragma unroll
                for (int fn = 0; fn < 4; ++fn) {
                    acc[fm][fn] = __builtin_amdgcn_mfma_f32_16x16x32_bf16(
                        ah[fm], bh[fn], acc[fm][fn], 0, 0, 0);
                    acc[fm][fn] = __builtin_amdgcn_mfma_f32_16x16x32_bf16(
                        al[fm], bh[fn], acc[fm][fn], 0, 0, 0);
                    acc[fm][fn] = __builtin_amdgcn_mfma_f32_16x16x32_bf16(
                        ah[fm], bl[fn], acc[fm][fn], 0, 0, 0);
                }
        }
#pragma unroll
        for (int fm = 0; fm < 4; ++fm) {
            const int row0 = bm + wr + fm * 16 + lhi * 4;
#pragma unroll
            for (int fn = 0; fn < 4; ++fn) {
                const int col = bn + wc + fn * 16 + l16;
#pragma unroll
                for (int r = 0; r < 4; ++r)
                    X[(size_t)(row0 + r) * 2048 + col] = acc[fm][fn][r];
            }
        }
    } else {
        // ---- z-half: 1-term bf16 (rows 2048.. of W) ----
        const int bnW = 2048 + (by - 16) * 128;
        const int bnC = (by - 16) * 128;
        for (int k0 = 0; k0 < Ktot; k0 += 32) {
            __syncthreads();
#pragma unroll
            for (int call = 0; call < 2; ++call) {
                const int row = srow0 + call * 64;
                const int wb  = ldsb0 + call * 4096;
                GLOAD_LDS16(Ah + (size_t)(bm + row) * Ktot + k0 + sks, (char*)Ash + wb);
                GLOAD_LDS16(Wh + (size_t)(bnW + row) * Ktot + k0 + sks, (char*)Bsh + wb);
            }
            __syncthreads();

            bf16x8 af[4], bfr[4];
#pragma unroll
            for (int f = 0; f < 4; ++f) {
                af[f]  = *(const bf16x8*)&Ash[(wr + f * 16 + l16) * 32 + lhi * 8];
                bfr[f] = *(const bf16x8*)&Bsh[(wc + f * 16 + l16) * 32 + lhi * 8];
            }
#pragma unroll
            for (int fm = 0; fm < 4; ++fm)
#pragma unroll
                for (int fn = 0; fn < 4; ++fn)
                    acc[fm][fn] = __builtin_amdgcn_mfma_f32_16x16x32_bf16(
                        af[fm], bfr[fn], acc[fm][fn], 0, 0, 0);
        }
#pragma unroll
        for (int fm = 0; fm < 4; ++fm) {
            const int row0 = bm + wr + fm * 16 + lhi * 4;
#pragma unroll
            for (int fn = 0; fn < 4; ++fn) {
                const int col = bnC + wc + fn * 16 + l16;
#pragma unroll
                for (int r = 0; r < 4; ++r)
                    Z[(size_t)(row0 + r) * 2048 + col] = acc[fm][fn][r];
            }
        }
    }
}

// ---------------------------------------------------------------------------
// Split-precision MFMA NT-GEMM (dt_proj).  128x128 tile, BK=32, 48 MFMA/step.
// EPI 2: v += bias[n]; softplus; store.
// ---------------------------------------------------------------------------
template<int EPI>
__global__ __launch_bounds__(256) void gemm_mfma3p(
    const bf16_t* __restrict__ Ah, const bf16_t* __restrict__ Al,
    const bf16_t* __restrict__ Bh, const bf16_t* __restrict__ Bl,
    float* __restrict__ C, const float* __restrict__ bias,
    int Ktot, int ldc)
{
    __shared__ __align__(16) bf16_t Ash[128 * 32];
    __shared__ __align__(16) bf16_t Asl[128 * 32];
    __shared__ __align__(16) bf16_t Bsh[128 * 32];
    __shared__ __align__(16) bf16_t Bsl[128 * 32];

    const int tid  = threadIdx.x;
    const int lane = tid & 63;
    const int w    = tid >> 6;
    const int wr   = (w >> 1) * 64;
    const int wc   = (w & 1) * 64;
    const int bm   = blockIdx.x * 128;
    const int bn   = blockIdx.y * 128;
    const int l16  = lane & 15;
    const int lhi  = lane >> 4;

    f32x4 acc[4][4];
#pragma unroll
    for (int i = 0; i < 4; ++i)
#pragma unroll
        for (int j = 0; j < 4; ++j)
#pragma unroll
            for (int r = 0; r < 4; ++r) acc[i][j][r] = 0.f;

    const int srow0 = tid >> 2;
    const int sks   = (tid & 3) << 3;
    const int ldsb0 = tid * 16;

    for (int k0 = 0; k0 < Ktot; k0 += 32) {
        __syncthreads();
#pragma unroll
        for (int call = 0; call < 2; ++call) {
            const int row = srow0 + call * 64;
            const int wb  = ldsb0 + call * 4096;
            const size_t aoff = (size_t)(bm + row) * Ktot + k0 + sks;
            const size_t boff = (size_t)(bn + row) * Ktot + k0 + sks;
            GLOAD_LDS16(Ah + aoff, (char*)Ash + wb);
            GLOAD_LDS16(Al + aoff, (char*)Asl + wb);
            GLOAD_LDS16(Bh + boff, (char*)Bsh + wb);
            GLOAD_LDS16(Bl + boff, (char*)Bsl + wb);
        }
        __syncthreads();

        bf16x8 ah[4], al[4], bh[4], bl[4];
#pragma unroll
        for (int f = 0; f < 4; ++f) {
            const int ar = (wr + f * 16 + l16) * 32 + lhi * 8;
            const int br = (wc + f * 16 + l16) * 32 + lhi * 8;
            ah[f] = *(const bf16x8*)&Ash[ar];
            al[f] = *(const bf16x8*)&Asl[ar];
            bh[f] = *(const bf16x8*)&Bsh[br];
            bl[f] = *(const bf16x8*)&Bsl[br];
        }
#pragma unroll
        for (int fm = 0; fm < 4; ++fm)
#pragma unroll
            for (int fn = 0; fn < 4; ++fn) {
                acc[fm][fn] = __builtin_amdgcn_mfma_f32_16x16x32_bf16(
                    ah[fm], bh[fn], acc[fm][fn], 0, 0, 0);
                acc[fm][fn] = __builtin_amdgcn_mfma_f32_16x16x32_bf16(
                    al[fm], bh[fn], acc[fm][fn], 0, 0, 0);
                acc[fm][fn] = __builtin_amdgcn_mfma_f32_16x16x32_bf16(
                    ah[fm], bl[fn], acc[fm][fn], 0, 0, 0);
            }
    }

#pragma unroll
    for (int fm = 0; fm < 4; ++fm) {
        const int row0 = bm + wr + fm * 16 + lhi * 4;
#pragma unroll
        for (int fn = 0; fn < 4; ++fn) {
            const int col = bn + wc + fn * 16 + l16;
#pragma unroll
            for (int r = 0; r < 4; ++r) {
                float v = acc[fm][fn][r];
                const size_t m = row0 + r;
                if (EPI == 2) {
                    v += bias[col];
                    v = (v > 20.f) ? v : log1pf(expf(v));
                }
                C[m * ldc + col] = v;
            }
        }
    }
}

// ---------------------------------------------------------------------------
// out_proj GEMM, BK=64: C = A.B^T (3-term), A fp32 reg-staged/split in-loop,
// B pre-split bf16 pair via global_load_lds.  64x128 tile, 4 waves (2x2),
// 48 MFMA per barrier-pair (2 ks-halves x 24).  LDS 48 KB.
// B LDS layout [ks][128][32]: dest is LANE-LINEAR (call*4096 + tid*16);
// the subtile permutation is applied to the per-lane GLOBAL source (m104).
// A staged via plain ds_write (scatter legal).
// ---------------------------------------------------------------------------
__global__ __launch_bounds__(256) void gemm_mfma3o64(
    const float* __restrict__ A,
    const bf16_t* __restrict__ Bh, const bf16_t* __restrict__ Bl,
    float* __restrict__ C, int K, int ldc)
{
    __shared__ __align__(16) bf16_t Ash[2 * 64 * 32];    // 8 KB
    __shared__ __align__(16) bf16_t Asl[2 * 64 * 32];
    __shared__ __align__(16) bf16_t Bsh[2 * 128 * 32];   // 16 KB
    __shared__ __align__(16) bf16_t Bsl[2 * 128 * 32];

    const int tid  = threadIdx.x;
    const int lane = tid & 63;
    const int w    = tid >> 6;
    const int wr   = (w >> 1) * 32;
    const int wc   = (w & 1) * 64;
    const int bm   = blockIdx.x * 64;
    const int bn   = blockIdx.y * 128;
    const int l16  = lane & 15;
    const int lhi  = lane >> 4;

    f32x4 acc[2][4];
#pragma unroll
    for (int i = 0; i < 2; ++i)
#pragma unroll
        for (int j = 0; j < 4; ++j)
#pragma unroll
            for (int r = 0; r < 4; ++r) acc[i][j][r] = 0.f;

    // A staging (plain ds_write): thread t -> row t>>2, 16 fp32 at col (t&3)*16.
    const int arow = tid >> 2;
    const int akc  = (tid & 3) << 4;
    const int aks  = akc >> 5;                 // 0 or 1
    const int aldb = aks * 4096 + arow * 64 + (akc & 31) * 2;  // byte base

    // B staging geometry: LDS dest linear, global source permuted.
    const int brow = tid >> 2;                 // 0..63 within half
    const int bch  = tid & 3;                  // 16B chunk within ks-half row

    for (int k0 = 0; k0 < K; k0 += 64) {
        __syncthreads();
        // B: 4 calls; call = {ks(2) x rowhalf(2)}; dest linear in tid.
#pragma unroll
        for (int call = 0; call < 4; ++call) {
            const int ks   = call >> 1;
            const int row  = (call & 1) * 64 + brow;
            const int wb   = call * 4096 + tid * 16;     // lane-linear dest
            const size_t boff = (size_t)(bn + row) * K + k0 + ks * 32 + bch * 8;
            GLOAD_LDS16(Bh + boff, (char*)Bsh + wb);
            GLOAD_LDS16(Bl + boff, (char*)Bsl + wb);
        }
        // A: 16 fp32 per thread, split to hi/lo, ds_write into [ks][64][32].
        {
            const float* ap = A + (size_t)(bm + arow) * K + k0 + akc;
            float fv[16];
#pragma unroll
            for (int q = 0; q < 4; ++q) {
                const float4 v = *(const float4*)(ap + q * 4);
                fv[q*4+0]=v.x; fv[q*4+1]=v.y; fv[q*4+2]=v.z; fv[q*4+3]=v.w;
            }
            bf16x8 hv0, lv0, hv1, lv1;
#pragma unroll
            for (int e = 0; e < 8; ++e) {
                bf16_t h = (bf16_t)fv[e];
                hv0[e] = h; lv0[e] = (bf16_t)(fv[e] - (float)h);
                h = (bf16_t)fv[8 + e];
                hv1[e] = h; lv1[e] = (bf16_t)(fv[8 + e] - (float)h);
            }
            *(bf16x8*)((char*)Ash + aldb)      = hv0;
            *(bf16x8*)((char*)Ash + aldb + 16) = hv1;
            *(bf16x8*)((char*)Asl + aldb)      = lv0;
            *(bf16x8*)((char*)Asl + aldb + 16) = lv1;
        }
        __syncthreads();

#pragma unroll
        for (int ks = 0; ks < 2; ++ks) {
            bf16x8 ah[2], al[2], bh[4], bl[4];
#pragma unroll
            for (int f = 0; f < 2; ++f) {
                const int ar = ks * 2048 + (wr + f * 16 + l16) * 32 + lhi * 8;
                ah[f] = *(const bf16x8*)&Ash[ar];
                al[f] = *(const bf16x8*)&Asl[ar];
            }
#pragma unroll
            for (int f = 0; f < 4; ++f) {
                const int br = ks * 4096 + (wc + f * 16 + l16) * 32 + lhi * 8;
                bh[f] = *(const bf16x8*)&Bsh[br];
                bl[f] = *(const bf16x8*)&Bsl[br];
            }
#pragma unroll
            for (int fm = 0; fm < 2; ++fm)
#pragma unroll
                for (int fn = 0; fn < 4; ++fn) {
                    acc[fm][fn] = __builtin_amdgcn_mfma_f32_16x16x32_bf16(
                        ah[fm], bh[fn], acc[fm][fn], 0, 0, 0);
                    acc[fm][fn] = __builtin_amdgcn_mfma_f32_16x16x32_bf16(
                        al[fm], bh[fn], acc[fm][fn], 0, 0, 0);
                    acc[fm][fn] = __builtin_amdgcn_mfma_f32_16x16x32_bf16(
                        ah[fm], bl[fn], acc[fm][fn], 0, 0, 0);
                }
        }
    }

#pragma unroll
    for (int fm = 0; fm < 2; ++fm) {
        const int row0 = bm + wr + fm * 16 + lhi * 4;
#pragma unroll
        for (int fn = 0; fn < 4; ++fn) {
            const int col = bn + wc + fn * 16 + l16;
#pragma unroll
            for (int r = 0; r < 4; ++r)
                C[(size_t)(row0 + r) * ldc + col] = acc[fm][fn][r];
        }
    }
}

// ---------------------------------------------------------------------------
// Tiled fp32 NT-GEMM with split-K (x_proj).  64x64 tile.
// ---------------------------------------------------------------------------
__global__ __launch_bounds__(256) void gemm_nt_sk(
    const float* __restrict__ A, const float* __restrict__ B,
    float* __restrict__ C,
    int N, int Ksplit, int lda, int ldb, int ldc, size_t partStride)
{
    __shared__ float As[16][68];
    __shared__ float Bs[16][68];

    const int tid = threadIdx.x;
    const int tx = tid & 15;
    const int ty = tid >> 4;
    const int bm = blockIdx.x * 64;
    const int bn = blockIdx.y * 64;

    const int r  = tid >> 2;
    const int kc = (tid & 3) << 2;

    float acc[4][4];
#pragma unroll
    for (int i = 0; i < 4; ++i)
#pragma unroll
        for (int j = 0; j < 4; ++j) acc[i][j] = 0.f;

    const int kBeg = blockIdx.z * Ksplit;
    const int kEnd = kBeg + Ksplit;

    for (int k0 = kBeg; k0 < kEnd; k0 += 16) {
        float4 av = *(const float4*)(A + (size_t)(bm + r) * lda + k0 + kc);
        const int cB = bn + r;
        float4 bv = make_float4(0.f, 0.f, 0.f, 0.f);
        if (cB < N) bv = *(const float4*)(B + (size_t)cB * ldb + k0 + kc);

        As[kc + 0][r] = av.x; As[kc + 1][r] = av.y;
        As[kc + 2][r] = av.z; As[kc + 3][r] = av.w;
        Bs[kc + 0][r] = bv.x; Bs[kc + 1][r] = bv.y;
        Bs[kc + 2][r] = bv.z; Bs[kc + 3][r] = bv.w;
        __syncthreads();

#pragma unroll
        for (int kk = 0; kk < 16; ++kk) {
            float4 a4 = *(const float4*)&As[kk][ty << 2];
            float4 b4 = *(const float4*)&Bs[kk][tx << 2];
            float a[4] = {a4.x, a4.y, a4.z, a4.w};
            float b[4] = {b4.x, b4.y, b4.z, b4.w};
#pragma unroll
            for (int i = 0; i < 4; ++i)
#pragma unroll
                for (int j = 0; j < 4; ++j)
                    acc[i][j] = fmaf(a[i], b[j], acc[i][j]);
        }
        __syncthreads();
    }

    float* Cp = C + (size_t)blockIdx.z * partStride;
#pragma unroll
    for (int i = 0; i < 4; ++i) {
        const int m = bm + (ty << 2) + i;
#pragma unroll
        for (int j = 0; j < 4; ++j) {
            const int n = bn + (tx << 2) + j;
            if (n < N) Cp[(size_t)m * ldc + n] = acc[i][j];
        }
    }
}

// ---------------------------------------------------------------------------
// Depthwise causal conv (width 4) + bias + SiLU, 4 channels per thread.
// ---------------------------------------------------------------------------
__global__ __launch_bounds__(256) void conv_silu4(
    const float* __restrict__ xin, const float* __restrict__ w,
    const float* __restrict__ bias, float* __restrict__ xout,
    int L, int D)
{
    const long long e4 = (long long)blockIdx.x * 256 + threadIdx.x;
    const int Dq = D >> 2;
    const int dq = (int)(e4 % Dq);
    const long long bl = e4 / Dq;
    const int l = (int)(bl % L);
    const int d = dq << 2;
    const long long base = bl * D + d;

    const float4 zero = make_float4(0.f, 0.f, 0.f, 0.f);
    const float4 x0 = *(const float4*)&xin[base];
    const float4 x1 = (l >= 1) ? *(const float4*)&xin[base - D]     : zero;
    const float4 x2 = (l >= 2) ? *(const float4*)&xin[base - 2*D]   : zero;
    const float4 x3 = (l >= 3) ? *(const float4*)&xin[base - 3*D]   : zero;
    const float4 bv = *(const float4*)&bias[d];

    float4 out;
    {
        const float4 wv = *(const float4*)&w[(d + 0) * 4];
        float acc = bv.x;
        acc = fmaf(wv.w, x0.x, acc); acc = fmaf(wv.z, x1.x, acc);
        acc = fmaf(wv.y, x2.x, acc); acc = fmaf(wv.x, x3.x, acc);
        out.x = acc / (1.f + __expf(-acc));
    }
    {
        const float4 wv = *(const float4*)&w[(d + 1) * 4];
        float acc = bv.y;
        acc = fmaf(wv.w, x0.y, acc); acc = fmaf(wv.z, x1.y, acc);
        acc = fmaf(wv.y, x2.y, acc); acc = fmaf(wv.x, x3.y, acc);
        out.y = acc / (1.f + __expf(-acc));
    }
    {
        const float4 wv = *(const float4*)&w[(d + 2) * 4];
        float acc = bv.z;
        acc = fmaf(wv.w, x0.z, acc); acc = fmaf(wv.z, x1.z, acc);
        acc = fmaf(wv.y, x2.z, acc); acc = fmaf(wv.x, x3.z, acc);
        out.z = acc / (1.f + __expf(-acc));
    }
    {
        const float4 wv = *(const float4*)&w[(d + 3) * 4];
        float acc = bv.w;
        acc = fmaf(wv.w, x0.w, acc); acc = fmaf(wv.z, x1.w, acc);
        acc = fmaf(wv.y, x2.w, acc); acc = fmaf(wv.x, x3.w, acc);
        out.w = acc / (1.f + __expf(-acc));
    }
    *(float4*)&xout[base] = out;
}

// ---------------------------------------------------------------------------
// Scan pass 1 (per-channel): thread owns channel d, 16 states in registers.
// ---------------------------------------------------------------------------
__global__ __launch_bounds__(256) void scan_local2(
    const float* __restrict__ xconv, const float* __restrict__ dt,
    const float* __restrict__ xdbl,  const float* __restrict__ A_log,
    float* __restrict__ Sbuf, float* __restrict__ Pbuf)
{
    __shared__ float Bs[CH][16];

    const int d = blockIdx.x * 256 + threadIdx.x;
    const int c = blockIdx.y;
    const int b = blockIdx.z;
    const long long rowBase = (long long)b * 4096 + (long long)c * CH;

#pragma unroll
    for (int k = 0; k < 2; ++k) {
        const int e = k * 256 + threadIdx.x;
        const int i = e >> 2, j = (e & 3) << 2;
        *(float4*)&Bs[i][j] = *(const float4*)&xdbl[(rowBase + i) * 96 + 64 + j];
    }
    __syncthreads();

    float a[16], S[16];
#pragma unroll
    for (int n = 0; n < 16; ++n) {
        a[n] = -__expf(A_log[d * 16 + n]);
        S[n] = 0.f;
    }
    float sumdt = 0.f;

    for (int i = 0; i < CH; ++i) {
        const long long row = rowBase + i;
        const float dtv = dt[row * 2048 + d];
        const float xv  = xconv[row * 2048 + d];
        const float u   = dtv * xv;
        sumdt += dtv;
#pragma unroll
        for (int n = 0; n < 16; ++n) {
            const float dA = __expf(dtv * a[n]);
            S[n] = fmaf(S[n], dA, u * Bs[i][n]);
        }
    }

    const size_t base = ((((size_t)b * NC + c) * 2048) + d) * 16;
#pragma unroll
    for (int k = 0; k < 4; ++k) {
        *(float4*)&Sbuf[base + k * 4] =
            make_float4(S[k*4], S[k*4+1], S[k*4+2], S[k*4+3]);
        *(float4*)&Pbuf[base + k * 4] =
            make_float4(__expf(sumdt * a[k*4]),   __expf(sumdt * a[k*4+1]),
                        __expf(sumdt * a[k*4+2]), __expf(sumdt * a[k*4+3]));
    }
}

// ---------------------------------------------------------------------------
// Pass 2: sequential prefix over chunks; Sbuf becomes chunk-entering state.
// ---------------------------------------------------------------------------
__global__ __launch_bounds__(256) void scan_chunk_prefix(
    float* __restrict__ Sbuf, const float* __restrict__ Pbuf)
{
    const int tid = blockIdx.x * 256 + threadIdx.x;
    const int b  = tid >> 15;
    const int dn = tid & 32767;

    float H = 0.f;
    for (int c = 0; c < NC; ++c) {
        const size_t idx = ((size_t)b * NC + c) * 32768 + dn;
        const float S = Sbuf[idx];
        const float P = Pbuf[idx];
        Sbuf[idx] = H;
        H = fmaf(P, H, S);
    }
}

// ---------------------------------------------------------------------------
// Scan pass 3 (per-channel): seeded with H, gate, fp32 y in-place to xconv.
// ---------------------------------------------------------------------------
__global__ __launch_bounds__(256) void scan_final2(
    const float* __restrict__ xconv, const float* __restrict__ dt,
    const float* __restrict__ xdbl,  const float* __restrict__ A_log,
    const float* __restrict__ Dp,    const float* __restrict__ z,
    const float* __restrict__ Hbuf,  float* __restrict__ y)
{
    __shared__ float BCs[CH][32];    // [l][0..15]=B, [l][16..31]=C

    const int d = blockIdx.x * 256 + threadIdx.x;
    const int c = blockIdx.y;
    const int b = blockIdx.z;
    const long long rowBase = (long long)b * 4096 + (long long)c * CH;

#pragma unroll
    for (int k = 0; k < 4; ++k) {
        const int e = k * 256 + threadIdx.x;
        const int i = e >> 3, j = (e & 7) << 2;
        *(float4*)&BCs[i][j] = *(const float4*)&xdbl[(rowBase + i) * 96 + 64 + j];
    }
    __syncthreads();

    float a[16], h[16];
    const size_t hbase = ((((size_t)b * NC + c) * 2048) + d) * 16;
#pragma unroll
    for (int k = 0; k < 4; ++k) {
        const float4 hv = *(const float4*)&Hbuf[hbase + k * 4];
        h[k*4] = hv.x; h[k*4+1] = hv.y; h[k*4+2] = hv.z; h[k*4+3] = hv.w;
    }
#pragma unroll
    for (int n = 0; n < 16; ++n) a[n] = -__expf(A_log[d * 16 + n]);
    const float Dv = Dp[d];

    for (int i = 0; i < CH; ++i) {
        const long long row = rowBase + i;
        const float dtv = dt[row * 2048 + d];
        const float xv  = xconv[row * 2048 + d];
        const float u   = dtv * xv;
        float acc = 0.f;
#pragma unroll
        for (int n = 0; n < 16; ++n) {
            const float dA = __expf(dtv * a[n]);
            h[n] = fmaf(h[n], dA, u * BCs[i][n]);
            acc  = fmaf(h[n], BCs[i][16 + n], acc);
        }
        const float zv = z[row * 2048 + d];
        float yv = acc + xv * Dv;
        yv = yv * (zv / (1.f + __expf(-zv)));
        y[row * 2048 + d] = yv;
    }
}

// ---------------------------------------------------------------------------
extern "C" void kernel_launch(void* const* d_in, const int* in_sizes, int n_in,
                              void* d_out, int out_size, void* d_ws, size_t ws_size,
                              hipStream_t stream)
{
    const float* hidden     = (const float*)d_in[0];
    const float* in_proj_w  = (const float*)d_in[1];
    const float* conv_w     = (const float*)d_in[2];
    const float* conv_b     = (const float*)d_in[3];
    const float* x_proj_w   = (const float*)d_in[4];
    const float* dt_proj_w  = (const float*)d_in[5];
    const float* dt_proj_b  = (const float*)d_in[6];
    const float* A_log      = (const float*)d_in[7];
    const float* Dvec       = (const float*)d_in[8];
    const float* out_proj_w = (const float*)d_in[9];
    float* out = (float*)d_out;

    const int L = 4096, dinner = 2048, dmodel = 1024;
    const int M = 2 * L;  // 8192

    // ---- workspace layout: EXACTLY R2's proven 221.25 MB footprint ----
    float* z     = (float*)d_ws;                       // M*2048 fp32
    float* xraw  = z     + (size_t)M * dinner;         // M*2048 (x, xproj parts, dt)
    float* xconv = xraw  + (size_t)M * dinner;         // M*2048 (hid-pair, xconv, y)
    float* xdbl  = xconv + (size_t)M * dinner;         // M*96
    float* Sbuf  = xdbl  + (size_t)M * 96;             // 2*NC*2048*16
    float* Pbuf  = Sbuf  + (size_t)2 * NC * dinner * 16;

    // lifetime-disjoint aliases (timeline):
    //  t0..in_proj : w1 pair = [Sbuf .. Pbuf end) 16.78 MB; hid pair in xconv
    //  post-in_proj: wd pair in Sbuf+2MB (w1 dead); dth/dtl in Sbuf+0..2MB
    //                (written at add8_split); both consumed by dt-gemm, all
    //                dead before scan_local2 writes Sbuf/Pbuf.
    bf16_t* w1_h  = (bf16_t*)Sbuf;
    bf16_t* w1_l  = w1_h + (size_t)2 * dinner * dmodel;
    bf16_t* hid_h = (bf16_t*)xconv;
    bf16_t* hid_l = hid_h + (size_t)M * dmodel;
    float*  xp_part = xraw;
    bf16_t* dth  = (bf16_t*)Sbuf;                      // [M][64] x2 = 2 MB
    bf16_t* dtl  = dth + (size_t)M * 64;
    bf16_t* wdh  = dtl + (size_t)M * 64;               // [2048][64] x2 = 0.5 MB
    bf16_t* wdl  = wdh + (size_t)dinner * 64;
    bf16_t* w2_h  = (bf16_t*)z;                        // split after scan consumed z
    bf16_t* w2_l  = w2_h + (size_t)dmodel * dinner;

    // ---- 0. fused t=0 splits: hidden + in_proj_w ----
    const int n4a = M * dmodel / 4;
    const int n4b = 2 * dinner * dmodel / 4;
    split2<<<(n4a + n4b + 255) / 256, 256, 0, stream>>>(
        hidden, hid_h, hid_l, n4a,
        in_proj_w, w1_h, w1_l, n4b);

    // ---- 1. in_proj fused (x-half 3-term | z-half 1-term) ----
    in_proj_fused<<<dim3(M / 128, 32), 256, 0, stream>>>(
        hid_h, hid_l, w1_h, w1_l, xraw, z, dmodel);

    // ---- 1b. split dt_proj_w (w1 now dead; R10-proven placement) ----
    split_hl<<<(dinner * 64 / 4 + 255) / 256, 256, 0, stream>>>(
        dt_proj_w, wdh, wdl, dinner * 64 / 4);

    // ---- 2. depthwise conv + bias + SiLU (x4 vectorized) ----
    conv_silu4<<<(M * (long long)dinner / 4) / 256, 256, 0, stream>>>(
        xraw, conv_w, conv_b, xconv, L, dinner);

    // ---- 3. x_proj (fp32, split-K=8): partials -> add8_split -> xdbl ----
    gemm_nt_sk<<<dim3(M / 64, 2, 8), 256, 0, stream>>>(
        xconv, x_proj_w, xp_part, 96, 2048 / 8, 2048, 2048, 96,
        (size_t)M * 96);
    add8_split<<<(M * 96 / 4 + 255) / 256, 256, 0, stream>>>(
        xp_part, xdbl, dth, dtl, M * 96 / 4, (size_t)M * 96 / 4);

    // ---- 4. dt_proj (3-term MFMA, K=64): softplus(dt@W^T + b) -> xraw ----
    gemm_mfma3p<2><<<dim3(M / 128, 2048 / 128), 256, 0, stream>>>(
        dth, dtl, wdh, wdl, xraw, dt_proj_b, 64, 2048);

    // ---- 5. chunked selective scan (per-channel register-state form) ----
    scan_local2<<<dim3(dinner / 256, NC, 2), 256, 0, stream>>>(
        xconv, xraw, xdbl, A_log, Sbuf, Pbuf);
    scan_chunk_prefix<<<256, 256, 0, stream>>>(Sbuf, Pbuf);
    scan_final2<<<dim3(dinner / 256, NC, 2), 256, 0, stream>>>(
        xconv, xraw, xdbl, A_log, Dvec, z, Sbuf, xconv);

    // ---- 5b. split out_proj_w into bf16 hi/lo (into z region, now dead) ----
    split_hl<<<(dmodel * dinner / 4 + 255) / 256, 256, 0, stream>>>(
        out_proj_w, w2_h, w2_l, dmodel * dinner / 4);

    // ---- 6. out_proj (BK=64, 48 MFMA/step): A=y fp32 reg-staged -> out ----
    gemm_mfma3o64<<<dim3(M / 64, 1024 / 128), 256, 0, stream>>>(
        xconv, w2_h, w2_l, out, dinner, 1024);
}

// Round 13
// 670.020 us; speedup vs baseline: 1.0337x; 1.0337x over previous
//
#include <hip/hip_runtime.h>
#include <cmath>

#define CH 128          // scan chunk length
#define NC 32           // 4096 / CH

typedef __bf16 bf16_t;
typedef __attribute__((ext_vector_type(8))) __bf16 bf16x8;
typedef __attribute__((ext_vector_type(4))) __bf16 bf16x4;
typedef __attribute__((ext_vector_type(4))) float f32x4;

// CK idiom: generic->AS1/AS3 via uintptr for global_load_lds (width 16).
// NOTE (m104): LDS dest must be LINEAR in lane order (base + lane*16);
// any layout permutation must be applied to the GLOBAL source address.
#define GLOAD_LDS16(gp, lp)                                                     \
    __builtin_amdgcn_global_load_lds(                                           \
        (const __attribute__((address_space(1))) unsigned int*)(uintptr_t)(gp), \
        (__attribute__((address_space(3))) unsigned int*)(uintptr_t)(lp),       \
        16, 0, 0)

// ---------------------------------------------------------------------------
// fp32 -> (hi, lo) bf16 split.  4 floats per thread.
// ---------------------------------------------------------------------------
__global__ __launch_bounds__(256) void split_hl(
    const float* __restrict__ in, bf16_t* __restrict__ hi,
    bf16_t* __restrict__ lo, int n4)
{
    const int i = blockIdx.x * 256 + threadIdx.x;
    if (i >= n4) return;
    const float4 v = ((const float4*)in)[i];
    const bf16_t h0 = (bf16_t)v.x, h1 = (bf16_t)v.y,
                 h2 = (bf16_t)v.z, h3 = (bf16_t)v.w;
    bf16x4 hv = {h0, h1, h2, h3};
    bf16x4 lv = {(bf16_t)(v.x - (float)h0), (bf16_t)(v.y - (float)h1),
                 (bf16_t)(v.z - (float)h2), (bf16_t)(v.w - (float)h3)};
    ((bf16x4*)hi)[i] = hv;
    ((bf16x4*)lo)[i] = lv;
}

// ---------------------------------------------------------------------------
// Fused t=0 splits: hidden -> hi ONLY (2-term in_proj drops the hidden-lo
// term); in_proj_w -> hi/lo pair.
// ---------------------------------------------------------------------------
__global__ __launch_bounds__(256) void split2m(
    const float* __restrict__ a, bf16_t* __restrict__ ah, int n4a,
    const float* __restrict__ b, bf16_t* __restrict__ bh, bf16_t* __restrict__ bl, int n4b)
{
    const int i = blockIdx.x * 256 + threadIdx.x;
    if (i < n4a) {
        const float4 v = ((const float4*)a)[i];
        bf16x4 hv = {(bf16_t)v.x, (bf16_t)v.y, (bf16_t)v.z, (bf16_t)v.w};
        ((bf16x4*)ah)[i] = hv;
    } else if (i < n4a + n4b) {
        const int j = i - n4a;
        const float4 v = ((const float4*)b)[j];
        const bf16_t h0 = (bf16_t)v.x, h1 = (bf16_t)v.y,
                     h2 = (bf16_t)v.z, h3 = (bf16_t)v.w;
        bf16x4 hv = {h0, h1, h2, h3};
        bf16x4 lv = {(bf16_t)(v.x - (float)h0), (bf16_t)(v.y - (float)h1),
                     (bf16_t)(v.z - (float)h2), (bf16_t)(v.w - (float)h3)};
        ((bf16x4*)bh)[j] = hv;
        ((bf16x4*)bl)[j] = lv;
    }
}

// ---------------------------------------------------------------------------
// x_proj split-K reduce + dt-slice hi/lo emit.
// ---------------------------------------------------------------------------
__global__ __launch_bounds__(256) void add8_split(
    const float* __restrict__ p, float* __restrict__ o,
    bf16_t* __restrict__ dth, bf16_t* __restrict__ dtl,
    int n4, size_t stride4)
{
    const int i = blockIdx.x * 256 + threadIdx.x;
    if (i >= n4) return;
    float4 s = make_float4(0.f, 0.f, 0.f, 0.f);
#pragma unroll
    for (int k = 0; k < 8; ++k) {
        const float4 v = ((const float4*)p)[(size_t)k * stride4 + i];
        s.x += v.x; s.y += v.y; s.z += v.z; s.w += v.w;
    }
    ((float4*)o)[i] = s;

    const int col4 = i % 24;
    if (col4 < 16) {
        const int row = i / 24;
        const bf16_t h0 = (bf16_t)s.x, h1 = (bf16_t)s.y,
                     h2 = (bf16_t)s.z, h3 = (bf16_t)s.w;
        bf16x4 hv = {h0, h1, h2, h3};
        bf16x4 lv = {(bf16_t)(s.x - (float)h0), (bf16_t)(s.y - (float)h1),
                     (bf16_t)(s.z - (float)h2), (bf16_t)(s.w - (float)h3)};
        ((bf16x4*)dth)[(size_t)row * 16 + col4] = hv;
        ((bf16x4*)dtl)[(size_t)row * 16 + col4] = lv;
    }
}

// ---------------------------------------------------------------------------
// Fused in_proj (2-term): blockIdx.y < 16 -> x-half: Ah.Bh + Ah.Bl
//                         blockIdx.y >= 16 -> z-half: Ah.Bh (gate-only use)
// 128x128 tile, BK=32, 4 waves, mfma_f32_16x16x32_bf16.  LDS 24 KB.
// ---------------------------------------------------------------------------
__global__ __launch_bounds__(256) void in_proj_fused(
    const bf16_t* __restrict__ Ah,
    const bf16_t* __restrict__ Wh, const bf16_t* __restrict__ Wl,
    float* __restrict__ X, float* __restrict__ Z, int Ktot)
{
    __shared__ __align__(16) bf16_t Ash[128 * 32];
    __shared__ __align__(16) bf16_t Bsh[128 * 32];
    __shared__ __align__(16) bf16_t Bsl[128 * 32];

    const int tid  = threadIdx.x;
    const int lane = tid & 63;
    const int w    = tid >> 6;
    const int wr   = (w >> 1) * 64;
    const int wc   = (w & 1) * 64;
    const int bm   = blockIdx.x * 128;
    const int by   = blockIdx.y;
    const int l16  = lane & 15;
    const int lhi  = lane >> 4;

    f32x4 acc[4][4];
#pragma unroll
    for (int i = 0; i < 4; ++i)
#pragma unroll
        for (int j = 0; j < 4; ++j)
#pragma unroll
            for (int r = 0; r < 4; ++r) acc[i][j][r] = 0.f;

    const int srow0 = tid >> 2;
    const int sks   = (tid & 3) << 3;
    const int ldsb0 = tid * 16;

    if (by < 16) {
        // ---- x-half: 2-term (Ah.Bh + Ah.Bl) ----
        const int bn = by * 128;
        for (int k0 = 0; k0 < Ktot; k0 += 32) {
            __syncthreads();
#pragma unroll
            for (int call = 0; call < 2; ++call) {
                const int row = srow0 + call * 64;
                const int wb  = ldsb0 + call * 4096;
                const size_t aoff = (size_t)(bm + row) * Ktot + k0 + sks;
                const size_t boff = (size_t)(bn + row) * Ktot + k0 + sks;
                GLOAD_LDS16(Ah + aoff, (char*)Ash + wb);
                GLOAD_LDS16(Wh + boff, (char*)Bsh + wb);
                GLOAD_LDS16(Wl + boff, (char*)Bsl + wb);
            }
            __syncthreads();

            bf16x8 ah[4], bh[4], bl[4];
#pragma unroll
            for (int f = 0; f < 4; ++f) {
                const int ar = (wr + f * 16 + l16) * 32 + lhi * 8;
                const int br = (wc + f * 16 + l16) * 32 + lhi * 8;
                ah[f] = *(const bf16x8*)&Ash[ar];
                bh[f] = *(const bf16x8*)&Bsh[br];
                bl[f] = *(const bf16x8*)&Bsl[br];
            }
#pragma unroll
            for (int fm = 0; fm < 4; ++fm)
#pragma unroll
                for (int fn = 0; fn < 4; ++fn) {
                    acc[fm][fn] = __builtin_amdgcn_mfma_f32_16x16x32_bf16(
                        ah[fm], bh[fn], acc[fm][fn], 0, 0, 0);
                    acc[fm][fn] = __builtin_amdgcn_mfma_f32_16x16x32_bf16(
                        ah[fm], bl[fn], acc[fm][fn], 0, 0, 0);
                }
        }
#pragma unroll
        for (int fm = 0; fm < 4; ++fm) {
            const int row0 = bm + wr + fm * 16 + lhi * 4;
#pragma unroll
            for (int fn = 0; fn < 4; ++fn) {
                const int col = bn + wc + fn * 16 + l16;
#pragma unroll
                for (int r = 0; r < 4; ++r)
                    X[(size_t)(row0 + r) * 2048 + col] = acc[fm][fn][r];
            }
        }
    } else {
        // ---- z-half: 1-term bf16 (rows 2048.. of W) ----
        const int bnW = 2048 + (by - 16) * 128;
        const int bnC = (by - 16) * 128;
        for (int k0 = 0; k0 < Ktot; k0 += 32) {
            __syncthreads();
#pragma unroll
            for (int call = 0; call < 2; ++call) {
                const int row = srow0 + call * 64;
                const int wb  = ldsb0 + call * 4096;
                GLOAD_LDS16(Ah + (size_t)(bm + row) * Ktot + k0 + sks, (char*)Ash + wb);
                GLOAD_LDS16(Wh + (size_t)(bnW + row) * Ktot + k0 + sks, (char*)Bsh + wb);
            }
            __syncthreads();

            bf16x8 af[4], bfr[4];
#pragma unroll
            for (int f = 0; f < 4; ++f) {
                af[f]  = *(const bf16x8*)&Ash[(wr + f * 16 + l16) * 32 + lhi * 8];
                bfr[f] = *(const bf16x8*)&Bsh[(wc + f * 16 + l16) * 32 + lhi * 8];
            }
#pragma unroll
            for (int fm = 0; fm < 4; ++fm)
#pragma unroll
                for (int fn = 0; fn < 4; ++fn)
                    acc[fm][fn] = __builtin_amdgcn_mfma_f32_16x16x32_bf16(
                        af[fm], bfr[fn], acc[fm][fn], 0, 0, 0);
        }
#pragma unroll
        for (int fm = 0; fm < 4; ++fm) {
            const int row0 = bm + wr + fm * 16 + lhi * 4;
#pragma unroll
            for (int fn = 0; fn < 4; ++fn) {
                const int col = bnC + wc + fn * 16 + l16;
#pragma unroll
                for (int r = 0; r < 4; ++r)
                    Z[(size_t)(row0 + r) * 2048 + col] = acc[fm][fn][r];
            }
        }
    }
}

// ---------------------------------------------------------------------------
// Split-precision MFMA NT-GEMM (dt_proj).  128x128 tile, BK=32, 48 MFMA/step.
// EPI 2: v += bias[n]; softplus; store.
// ---------------------------------------------------------------------------
template<int EPI>
__global__ __launch_bounds__(256) void gemm_mfma3p(
    const bf16_t* __restrict__ Ah, const bf16_t* __restrict__ Al,
    const bf16_t* __restrict__ Bh, const bf16_t* __restrict__ Bl,
    float* __restrict__ C, const float* __restrict__ bias,
    int Ktot, int ldc)
{
    __shared__ __align__(16) bf16_t Ash[128 * 32];
    __shared__ __align__(16) bf16_t Asl[128 * 32];
    __shared__ __align__(16) bf16_t Bsh[128 * 32];
    __shared__ __align__(16) bf16_t Bsl[128 * 32];

    const int tid  = threadIdx.x;
    const int lane = tid & 63;
    const int w    = tid >> 6;
    const int wr   = (w >> 1) * 64;
    const int wc   = (w & 1) * 64;
    const int bm   = blockIdx.x * 128;
    const int bn   = blockIdx.y * 128;
    const int l16  = lane & 15;
    const int lhi  = lane >> 4;

    f32x4 acc[4][4];
#pragma unroll
    for (int i = 0; i < 4; ++i)
#pragma unroll
        for (int j = 0; j < 4; ++j)
#pragma unroll
            for (int r = 0; r < 4; ++r) acc[i][j][r] = 0.f;

    const int srow0 = tid >> 2;
    const int sks   = (tid & 3) << 3;
    const int ldsb0 = tid * 16;

    for (int k0 = 0; k0 < Ktot; k0 += 32) {
        __syncthreads();
#pragma unroll
        for (int call = 0; call < 2; ++call) {
            const int row = srow0 + call * 64;
            const int wb  = ldsb0 + call * 4096;
            const size_t aoff = (size_t)(bm + row) * Ktot + k0 + sks;
            const size_t boff = (size_t)(bn + row) * Ktot + k0 + sks;
            GLOAD_LDS16(Ah + aoff, (char*)Ash + wb);
            GLOAD_LDS16(Al + aoff, (char*)Asl + wb);
            GLOAD_LDS16(Bh + boff, (char*)Bsh + wb);
            GLOAD_LDS16(Bl + boff, (char*)Bsl + wb);
        }
        __syncthreads();

        bf16x8 ah[4], al[4], bh[4], bl[4];
#pragma unroll
        for (int f = 0; f < 4; ++f) {
            const int ar = (wr + f * 16 + l16) * 32 + lhi * 8;
            const int br = (wc + f * 16 + l16) * 32 + lhi * 8;
            ah[f] = *(const bf16x8*)&Ash[ar];
            al[f] = *(const bf16x8*)&Asl[ar];
            bh[f] = *(const bf16x8*)&Bsh[br];
            bl[f] = *(const bf16x8*)&Bsl[br];
        }
#pragma unroll
        for (int fm = 0; fm < 4; ++fm)
#pragma unroll
            for (int fn = 0; fn < 4; ++fn) {
                acc[fm][fn] = __builtin_amdgcn_mfma_f32_16x16x32_bf16(
                    ah[fm], bh[fn], acc[fm][fn], 0, 0, 0);
                acc[fm][fn] = __builtin_amdgcn_mfma_f32_16x16x32_bf16(
                    al[fm], bh[fn], acc[fm][fn], 0, 0, 0);
                acc[fm][fn] = __builtin_amdgcn_mfma_f32_16x16x32_bf16(
                    ah[fm], bl[fn], acc[fm][fn], 0, 0, 0);
            }
    }

#pragma unroll
    for (int fm = 0; fm < 4; ++fm) {
        const int row0 = bm + wr + fm * 16 + lhi * 4;
#pragma unroll
        for (int fn = 0; fn < 4; ++fn) {
            const int col = bn + wc + fn * 16 + l16;
#pragma unroll
            for (int r = 0; r < 4; ++r) {
                float v = acc[fm][fn][r];
                const size_t m = row0 + r;
                if (EPI == 2) {
                    v += bias[col];
                    v = (v > 20.f) ? v : log1pf(expf(v));
                }
                C[m * ldc + col] = v;
            }
        }
    }
}

// ---------------------------------------------------------------------------
// out_proj GEMM, BK=64: C = A.B^T (3-term), A fp32 reg-staged/split in-loop,
// B pre-split bf16 pair via global_load_lds.  64x128 tile, 4 waves (2x2),
// 48 MFMA per barrier-pair.  LDS 48 KB.  B dest lane-linear (m104);
// subtile permutation on the global source.  A via plain ds_write.
// ---------------------------------------------------------------------------
__global__ __launch_bounds__(256) void gemm_mfma3o64(
    const float* __restrict__ A,
    const bf16_t* __restrict__ Bh, const bf16_t* __restrict__ Bl,
    float* __restrict__ C, int K, int ldc)
{
    __shared__ __align__(16) bf16_t Ash[2 * 64 * 32];
    __shared__ __align__(16) bf16_t Asl[2 * 64 * 32];
    __shared__ __align__(16) bf16_t Bsh[2 * 128 * 32];
    __shared__ __align__(16) bf16_t Bsl[2 * 128 * 32];

    const int tid  = threadIdx.x;
    const int lane = tid & 63;
    const int w    = tid >> 6;
    const int wr   = (w >> 1) * 32;
    const int wc   = (w & 1) * 64;
    const int bm   = blockIdx.x * 64;
    const int bn   = blockIdx.y * 128;
    const int l16  = lane & 15;
    const int lhi  = lane >> 4;

    f32x4 acc[2][4];
#pragma unroll
    for (int i = 0; i < 2; ++i)
#pragma unroll
        for (int j = 0; j < 4; ++j)
#pragma unroll
            for (int r = 0; r < 4; ++r) acc[i][j][r] = 0.f;

    const int arow = tid >> 2;
    const int akc  = (tid & 3) << 4;
    const int aks  = akc >> 5;
    const int aldb = aks * 4096 + arow * 64 + (akc & 31) * 2;

    const int brow = tid >> 2;
    const int bch  = tid & 3;

    for (int k0 = 0; k0 < K; k0 += 64) {
        __syncthreads();
#pragma unroll
        for (int call = 0; call < 4; ++call) {
            const int ks   = call >> 1;
            const int row  = (call & 1) * 64 + brow;
            const int wb   = call * 4096 + tid * 16;     // lane-linear dest
            const size_t boff = (size_t)(bn + row) * K + k0 + ks * 32 + bch * 8;
            GLOAD_LDS16(Bh + boff, (char*)Bsh + wb);
            GLOAD_LDS16(Bl + boff, (char*)Bsl + wb);
        }
        {
            const float* ap = A + (size_t)(bm + arow) * K + k0 + akc;
            float fv[16];
#pragma unroll
            for (int q = 0; q < 4; ++q) {
                const float4 v = *(const float4*)(ap + q * 4);
                fv[q*4+0]=v.x; fv[q*4+1]=v.y; fv[q*4+2]=v.z; fv[q*4+3]=v.w;
            }
            bf16x8 hv0, lv0, hv1, lv1;
#pragma unroll
            for (int e = 0; e < 8; ++e) {
                bf16_t h = (bf16_t)fv[e];
                hv0[e] = h; lv0[e] = (bf16_t)(fv[e] - (float)h);
                h = (bf16_t)fv[8 + e];
                hv1[e] = h; lv1[e] = (bf16_t)(fv[8 + e] - (float)h);
            }
            *(bf16x8*)((char*)Ash + aldb)      = hv0;
            *(bf16x8*)((char*)Ash + aldb + 16) = hv1;
            *(bf16x8*)((char*)Asl + aldb)      = lv0;
            *(bf16x8*)((char*)Asl + aldb + 16) = lv1;
        }
        __syncthreads();

#pragma unroll
        for (int ks = 0; ks < 2; ++ks) {
            bf16x8 ah[2], al[2], bh[4], bl[4];
#pragma unroll
            for (int f = 0; f < 2; ++f) {
                const int ar = ks * 2048 + (wr + f * 16 + l16) * 32 + lhi * 8;
                ah[f] = *(const bf16x8*)&Ash[ar];
                al[f] = *(const bf16x8*)&Asl[ar];
            }
#pragma unroll
            for (int f = 0; f < 4; ++f) {
                const int br = ks * 4096 + (wc + f * 16 + l16) * 32 + lhi * 8;
                bh[f] = *(const bf16x8*)&Bsh[br];
                bl[f] = *(const bf16x8*)&Bsl[br];
            }
#pragma unroll
            for (int fm = 0; fm < 2; ++fm)
#pragma unroll
                for (int fn = 0; fn < 4; ++fn) {
                    acc[fm][fn] = __builtin_amdgcn_mfma_f32_16x16x32_bf16(
                        ah[fm], bh[fn], acc[fm][fn], 0, 0, 0);
                    acc[fm][fn] = __builtin_amdgcn_mfma_f32_16x16x32_bf16(
                        al[fm], bh[fn], acc[fm][fn], 0, 0, 0);
                    acc[fm][fn] = __builtin_amdgcn_mfma_f32_16x16x32_bf16(
                        ah[fm], bl[fn], acc[fm][fn], 0, 0, 0);
                }
        }
    }

#pragma unroll
    for (int fm = 0; fm < 2; ++fm) {
        const int row0 = bm + wr + fm * 16 + lhi * 4;
#pragma unroll
        for (int fn = 0; fn < 4; ++fn) {
            const int col = bn + wc + fn * 16 + l16;
#pragma unroll
            for (int r = 0; r < 4; ++r)
                C[(size_t)(row0 + r) * ldc + col] = acc[fm][fn][r];
        }
    }
}

// ---------------------------------------------------------------------------
// Tiled fp32 NT-GEMM with split-K (x_proj).  64x64 tile.
// ---------------------------------------------------------------------------
__global__ __launch_bounds__(256) void gemm_nt_sk(
    const float* __restrict__ A, const float* __restrict__ B,
    float* __restrict__ C,
    int N, int Ksplit, int lda, int ldb, int ldc, size_t partStride)
{
    __shared__ float As[16][68];
    __shared__ float Bs[16][68];

    const int tid = threadIdx.x;
    const int tx = tid & 15;
    const int ty = tid >> 4;
    const int bm = blockIdx.x * 64;
    const int bn = blockIdx.y * 64;

    const int r  = tid >> 2;
    const int kc = (tid & 3) << 2;

    float acc[4][4];
#pragma unroll
    for (int i = 0; i < 4; ++i)
#pragma unroll
        for (int j = 0; j < 4; ++j) acc[i][j] = 0.f;

    const int kBeg = blockIdx.z * Ksplit;
    const int kEnd = kBeg + Ksplit;

    for (int k0 = kBeg; k0 < kEnd; k0 += 16) {
        float4 av = *(const float4*)(A + (size_t)(bm + r) * lda + k0 + kc);
        const int cB = bn + r;
        float4 bv = make_float4(0.f, 0.f, 0.f, 0.f);
        if (cB < N) bv = *(const float4*)(B + (size_t)cB * ldb + k0 + kc);

        As[kc + 0][r] = av.x; As[kc + 1][r] = av.y;
        As[kc + 2][r] = av.z; As[kc + 3][r] = av.w;
        Bs[kc + 0][r] = bv.x; Bs[kc + 1][r] = bv.y;
        Bs[kc + 2][r] = bv.z; Bs[kc + 3][r] = bv.w;
        __syncthreads();

#pragma unroll
        for (int kk = 0; kk < 16; ++kk) {
            float4 a4 = *(const float4*)&As[kk][ty << 2];
            float4 b4 = *(const float4*)&Bs[kk][tx << 2];
            float a[4] = {a4.x, a4.y, a4.z, a4.w};
            float b[4] = {b4.x, b4.y, b4.z, b4.w};
#pragma unroll
            for (int i = 0; i < 4; ++i)
#pragma unroll
                for (int j = 0; j < 4; ++j)
                    acc[i][j] = fmaf(a[i], b[j], acc[i][j]);
        }
        __syncthreads();
    }

    float* Cp = C + (size_t)blockIdx.z * partStride;
#pragma unroll
    for (int i = 0; i < 4; ++i) {
        const int m = bm + (ty << 2) + i;
#pragma unroll
        for (int j = 0; j < 4; ++j) {
            const int n = bn + (tx << 2) + j;
            if (n < N) Cp[(size_t)m * ldc + n] = acc[i][j];
        }
    }
}

// ---------------------------------------------------------------------------
// Depthwise causal conv (width 4) + bias + SiLU, 4 channels per thread.
// ---------------------------------------------------------------------------
__global__ __launch_bounds__(256) void conv_silu4(
    const float* __restrict__ xin, const float* __restrict__ w,
    const float* __restrict__ bias, float* __restrict__ xout,
    int L, int D)
{
    const long long e4 = (long long)blockIdx.x * 256 + threadIdx.x;
    const int Dq = D >> 2;
    const int dq = (int)(e4 % Dq);
    const long long bl = e4 / Dq;
    const int l = (int)(bl % L);
    const int d = dq << 2;
    const long long base = bl * D + d;

    const float4 zero = make_float4(0.f, 0.f, 0.f, 0.f);
    const float4 x0 = *(const float4*)&xin[base];
    const float4 x1 = (l >= 1) ? *(const float4*)&xin[base - D]     : zero;
    const float4 x2 = (l >= 2) ? *(const float4*)&xin[base - 2*D]   : zero;
    const float4 x3 = (l >= 3) ? *(const float4*)&xin[base - 3*D]   : zero;
    const float4 bv = *(const float4*)&bias[d];

    float4 out;
    {
        const float4 wv = *(const float4*)&w[(d + 0) * 4];
        float acc = bv.x;
        acc = fmaf(wv.w, x0.x, acc); acc = fmaf(wv.z, x1.x, acc);
        acc = fmaf(wv.y, x2.x, acc); acc = fmaf(wv.x, x3.x, acc);
        out.x = acc / (1.f + __expf(-acc));
    }
    {
        const float4 wv = *(const float4*)&w[(d + 1) * 4];
        float acc = bv.y;
        acc = fmaf(wv.w, x0.y, acc); acc = fmaf(wv.z, x1.y, acc);
        acc = fmaf(wv.y, x2.y, acc); acc = fmaf(wv.x, x3.y, acc);
        out.y = acc / (1.f + __expf(-acc));
    }
    {
        const float4 wv = *(const float4*)&w[(d + 2) * 4];
        float acc = bv.z;
        acc = fmaf(wv.w, x0.z, acc); acc = fmaf(wv.z, x1.z, acc);
        acc = fmaf(wv.y, x2.z, acc); acc = fmaf(wv.x, x3.z, acc);
        out.z = acc / (1.f + __expf(-acc));
    }
    {
        const float4 wv = *(const float4*)&w[(d + 3) * 4];
        float acc = bv.w;
        acc = fmaf(wv.w, x0.w, acc); acc = fmaf(wv.z, x1.w, acc);
        acc = fmaf(wv.y, x2.w, acc); acc = fmaf(wv.x, x3.w, acc);
        out.w = acc / (1.f + __expf(-acc));
    }
    *(float4*)&xout[base] = out;
}

// ---------------------------------------------------------------------------
// Scan pass 1 (per-channel): thread owns channel d, 16 states in registers.
// ---------------------------------------------------------------------------
__global__ __launch_bounds__(256) void scan_local2(
    const float* __restrict__ xconv, const float* __restrict__ dt,
    const float* __restrict__ xdbl,  const float* __restrict__ A_log,
    float* __restrict__ Sbuf, float* __restrict__ Pbuf)
{
    __shared__ float Bs[CH][16];

    const int d = blockIdx.x * 256 + threadIdx.x;
    const int c = blockIdx.y;
    const int b = blockIdx.z;
    const long long rowBase = (long long)b * 4096 + (long long)c * CH;

#pragma unroll
    for (int k = 0; k < 2; ++k) {
        const int e = k * 256 + threadIdx.x;
        const int i = e >> 2, j = (e & 3) << 2;
        *(float4*)&Bs[i][j] = *(const float4*)&xdbl[(rowBase + i) * 96 + 64 + j];
    }
    __syncthreads();

    float a[16], S[16];
#pragma unroll
    for (int n = 0; n < 16; ++n) {
        a[n] = -__expf(A_log[d * 16 + n]);
        S[n] = 0.f;
    }
    float sumdt = 0.f;

    for (int i = 0; i < CH; ++i) {
        const long long row = rowBase + i;
        const float dtv = dt[row * 2048 + d];
        const float xv  = xconv[row * 2048 + d];
        const float u   = dtv * xv;
        sumdt += dtv;
#pragma unroll
        for (int n = 0; n < 16; ++n) {
            const float dA = __expf(dtv * a[n]);
            S[n] = fmaf(S[n], dA, u * Bs[i][n]);
        }
    }

    const size_t base = ((((size_t)b * NC + c) * 2048) + d) * 16;
#pragma unroll
    for (int k = 0; k < 4; ++k) {
        *(float4*)&Sbuf[base + k * 4] =
            make_float4(S[k*4], S[k*4+1], S[k*4+2], S[k*4+3]);
        *(float4*)&Pbuf[base + k * 4] =
            make_float4(__expf(sumdt * a[k*4]),   __expf(sumdt * a[k*4+1]),
                        __expf(sumdt * a[k*4+2]), __expf(sumdt * a[k*4+3]));
    }
}

// ---------------------------------------------------------------------------
// Pass 2: sequential prefix over chunks; Sbuf becomes chunk-entering state.
// ---------------------------------------------------------------------------
__global__ __launch_bounds__(256) void scan_chunk_prefix(
    float* __restrict__ Sbuf, const float* __restrict__ Pbuf)
{
    const int tid = blockIdx.x * 256 + threadIdx.x;
    const int b  = tid >> 15;
    const int dn = tid & 32767;

    float H = 0.f;
    for (int c = 0; c < NC; ++c) {
        const size_t idx = ((size_t)b * NC + c) * 32768 + dn;
        const float S = Sbuf[idx];
        const float P = Pbuf[idx];
        Sbuf[idx] = H;
        H = fmaf(P, H, S);
    }
}

// ---------------------------------------------------------------------------
// Scan pass 3 (per-channel): seeded with H, gate, fp32 y in-place to xconv.
// ---------------------------------------------------------------------------
__global__ __launch_bounds__(256) void scan_final2(
    const float* __restrict__ xconv, const float* __restrict__ dt,
    const float* __restrict__ xdbl,  const float* __restrict__ A_log,
    const float* __restrict__ Dp,    const float* __restrict__ z,
    const float* __restrict__ Hbuf,  float* __restrict__ y)
{
    __shared__ float BCs[CH][32];    // [l][0..15]=B, [l][16..31]=C

    const int d = blockIdx.x * 256 + threadIdx.x;
    const int c = blockIdx.y;
    const int b = blockIdx.z;
    const long long rowBase = (long long)b * 4096 + (long long)c * CH;

#pragma unroll
    for (int k = 0; k < 4; ++k) {
        const int e = k * 256 + threadIdx.x;
        const int i = e >> 3, j = (e & 7) << 2;
        *(float4*)&BCs[i][j] = *(const float4*)&xdbl[(rowBase + i) * 96 + 64 + j];
    }
    __syncthreads();

    float a[16], h[16];
    const size_t hbase = ((((size_t)b * NC + c) * 2048) + d) * 16;
#pragma unroll
    for (int k = 0; k < 4; ++k) {
        const float4 hv = *(const float4*)&Hbuf[hbase + k * 4];
        h[k*4] = hv.x; h[k*4+1] = hv.y; h[k*4+2] = hv.z; h[k*4+3] = hv.w;
    }
#pragma unroll
    for (int n = 0; n < 16; ++n) a[n] = -__expf(A_log[d * 16 + n]);
    const float Dv = Dp[d];

    for (int i = 0; i < CH; ++i) {
        const long long row = rowBase + i;
        const float dtv = dt[row * 2048 + d];
        const float xv  = xconv[row * 2048 + d];
        const float u   = dtv * xv;
        float acc = 0.f;
#pragma unroll
        for (int n = 0; n < 16; ++n) {
            const float dA = __expf(dtv * a[n]);
            h[n] = fmaf(h[n], dA, u * BCs[i][n]);
            acc  = fmaf(h[n], BCs[i][16 + n], acc);
        }
        const float zv = z[row * 2048 + d];
        float yv = acc + xv * Dv;
        yv = yv * (zv / (1.f + __expf(-zv)));
        y[row * 2048 + d] = yv;
    }
}

// ---------------------------------------------------------------------------
extern "C" void kernel_launch(void* const* d_in, const int* in_sizes, int n_in,
                              void* d_out, int out_size, void* d_ws, size_t ws_size,
                              hipStream_t stream)
{
    const float* hidden     = (const float*)d_in[0];
    const float* in_proj_w  = (const float*)d_in[1];
    const float* conv_w     = (const float*)d_in[2];
    const float* conv_b     = (const float*)d_in[3];
    const float* x_proj_w   = (const float*)d_in[4];
    const float* dt_proj_w  = (const float*)d_in[5];
    const float* dt_proj_b  = (const float*)d_in[6];
    const float* A_log      = (const float*)d_in[7];
    const float* Dvec       = (const float*)d_in[8];
    const float* out_proj_w = (const float*)d_in[9];
    float* out = (float*)d_out;

    const int L = 4096, dinner = 2048, dmodel = 1024;
    const int M = 2 * L;  // 8192

    // ---- workspace layout: EXACTLY R2's proven 221.25 MB footprint ----
    float* z     = (float*)d_ws;                       // M*2048 fp32
    float* xraw  = z     + (size_t)M * dinner;         // M*2048 (x, xproj parts, dt)
    float* xconv = xraw  + (size_t)M * dinner;         // M*2048 (hid, xconv, y)
    float* xdbl  = xconv + (size_t)M * dinner;         // M*96
    float* Sbuf  = xdbl  + (size_t)M * 96;             // 2*NC*2048*16
    float* Pbuf  = Sbuf  + (size_t)2 * NC * dinner * 16;

    // lifetime-disjoint aliases (timeline):
    //  t0..in_proj : w1 pair = [Sbuf .. Pbuf end) 16.78 MB; hid_h in xconv
    //  post-in_proj: dth/dtl in Sbuf+0..2MB (add8_split), wd pair at +2MB
    //                (w1 dead); all dead before scan_local2 writes Sbuf/Pbuf.
    bf16_t* w1_h  = (bf16_t*)Sbuf;
    bf16_t* w1_l  = w1_h + (size_t)2 * dinner * dmodel;
    bf16_t* hid_h = (bf16_t*)xconv;                    // hi only (2-term in_proj)
    float*  xp_part = xraw;
    bf16_t* dth  = (bf16_t*)Sbuf;                      // [M][64] x2 = 2 MB
    bf16_t* dtl  = dth + (size_t)M * 64;
    bf16_t* wdh  = dtl + (size_t)M * 64;               // [2048][64] x2 = 0.5 MB
    bf16_t* wdl  = wdh + (size_t)dinner * 64;
    bf16_t* w2_h  = (bf16_t*)z;                        // split after scan consumed z
    bf16_t* w2_l  = w2_h + (size_t)dmodel * dinner;

    // ---- 0. fused t=0 splits: hidden (hi only) + in_proj_w (pair) ----
    const int n4a = M * dmodel / 4;
    const int n4b = 2 * dinner * dmodel / 4;
    split2m<<<(n4a + n4b + 255) / 256, 256, 0, stream>>>(
        hidden, hid_h, n4a,
        in_proj_w, w1_h, w1_l, n4b);

    // ---- 1. in_proj fused (x-half 2-term | z-half 1-term) ----
    in_proj_fused<<<dim3(M / 128, 32), 256, 0, stream>>>(
        hid_h, w1_h, w1_l, xraw, z, dmodel);

    // ---- 1b. split dt_proj_w (w1 now dead) ----
    split_hl<<<(dinner * 64 / 4 + 255) / 256, 256, 0, stream>>>(
        dt_proj_w, wdh, wdl, dinner * 64 / 4);

    // ---- 2. depthwise conv + bias + SiLU (x4 vectorized) ----
    conv_silu4<<<(M * (long long)dinner / 4) / 256, 256, 0, stream>>>(
        xraw, conv_w, conv_b, xconv, L, dinner);

    // ---- 3. x_proj (fp32, split-K=8): partials -> add8_split -> xdbl ----
    gemm_nt_sk<<<dim3(M / 64, 2, 8), 256, 0, stream>>>(
        xconv, x_proj_w, xp_part, 96, 2048 / 8, 2048, 2048, 96,
        (size_t)M * 96);
    add8_split<<<(M * 96 / 4 + 255) / 256, 256, 0, stream>>>(
        xp_part, xdbl, dth, dtl, M * 96 / 4, (size_t)M * 96 / 4);

    // ---- 4. dt_proj (3-term MFMA, K=64): softplus(dt@W^T + b) -> xraw ----
    gemm_mfma3p<2><<<dim3(M / 128, 2048 / 128), 256, 0, stream>>>(
        dth, dtl, wdh, wdl, xraw, dt_proj_b, 64, 2048);

    // ---- 5. chunked selective scan (per-channel register-state form) ----
    scan_local2<<<dim3(dinner / 256, NC, 2), 256, 0, stream>>>(
        xconv, xraw, xdbl, A_log, Sbuf, Pbuf);
    scan_chunk_prefix<<<256, 256, 0, stream>>>(Sbuf, Pbuf);
    scan_final2<<<dim3(dinner / 256, NC, 2), 256, 0, stream>>>(
        xconv, xraw, xdbl, A_log, Dvec, z, Sbuf, xconv);

    // ---- 5b. split out_proj_w into bf16 hi/lo (into z region, now dead) ----
    split_hl<<<(dmodel * dinner / 4 + 255) / 256, 256, 0, stream>>>(
        out_proj_w, w2_h, w2_l, dmodel * dinner / 4);

    // ---- 6. out_proj (BK=64, 48 MFMA/step): A=y fp32 reg-staged -> out ----
    gemm_mfma3o64<<<dim3(M / 64, 1024 / 128), 256, 0, stream>>>(
        xconv, w2_h, w2_l, out, dinner, 1024);
}

// Round 14
// 642.593 us; speedup vs baseline: 1.0778x; 1.0427x over previous
//
#include <hip/hip_runtime.h>
#include <cmath>

#define CH 128          // scan chunk length
#define NC 32           // 4096 / CH

typedef __bf16 bf16_t;
typedef __attribute__((ext_vector_type(8))) __bf16 bf16x8;
typedef __attribute__((ext_vector_type(4))) __bf16 bf16x4;
typedef __attribute__((ext_vector_type(4))) float f32x4;

// CK idiom: generic->AS1/AS3 via uintptr for global_load_lds (width 16).
// NOTE (m104): LDS dest must be LINEAR in lane order (base + lane*16);
// any layout permutation must be applied to the GLOBAL source address.
#define GLOAD_LDS16(gp, lp)                                                     \
    __builtin_amdgcn_global_load_lds(                                           \
        (const __attribute__((address_space(1))) unsigned int*)(uintptr_t)(gp), \
        (__attribute__((address_space(3))) unsigned int*)(uintptr_t)(lp),       \
        16, 0, 0)

// ---------------------------------------------------------------------------
// fp32 -> (hi, lo) bf16 split.  4 floats per thread.
// ---------------------------------------------------------------------------
__global__ __launch_bounds__(256) void split_hl(
    const float* __restrict__ in, bf16_t* __restrict__ hi,
    bf16_t* __restrict__ lo, int n4)
{
    const int i = blockIdx.x * 256 + threadIdx.x;
    if (i >= n4) return;
    const float4 v = ((const float4*)in)[i];
    const bf16_t h0 = (bf16_t)v.x, h1 = (bf16_t)v.y,
                 h2 = (bf16_t)v.z, h3 = (bf16_t)v.w;
    bf16x4 hv = {h0, h1, h2, h3};
    bf16x4 lv = {(bf16_t)(v.x - (float)h0), (bf16_t)(v.y - (float)h1),
                 (bf16_t)(v.z - (float)h2), (bf16_t)(v.w - (float)h3)};
    ((bf16x4*)hi)[i] = hv;
    ((bf16x4*)lo)[i] = lv;
}

// ---------------------------------------------------------------------------
// Fused t=0 splits: hidden -> hi ONLY; in_proj_w -> hi/lo pair.
// ---------------------------------------------------------------------------
__global__ __launch_bounds__(256) void split2m(
    const float* __restrict__ a, bf16_t* __restrict__ ah, int n4a,
    const float* __restrict__ b, bf16_t* __restrict__ bh, bf16_t* __restrict__ bl, int n4b)
{
    const int i = blockIdx.x * 256 + threadIdx.x;
    if (i < n4a) {
        const float4 v = ((const float4*)a)[i];
        bf16x4 hv = {(bf16_t)v.x, (bf16_t)v.y, (bf16_t)v.z, (bf16_t)v.w};
        ((bf16x4*)ah)[i] = hv;
    } else if (i < n4a + n4b) {
        const int j = i - n4a;
        const float4 v = ((const float4*)b)[j];
        const bf16_t h0 = (bf16_t)v.x, h1 = (bf16_t)v.y,
                     h2 = (bf16_t)v.z, h3 = (bf16_t)v.w;
        bf16x4 hv = {h0, h1, h2, h3};
        bf16x4 lv = {(bf16_t)(v.x - (float)h0), (bf16_t)(v.y - (float)h1),
                     (bf16_t)(v.z - (float)h2), (bf16_t)(v.w - (float)h3)};
        ((bf16x4*)bh)[j] = hv;
        ((bf16x4*)bl)[j] = lv;
    }
}

// ---------------------------------------------------------------------------
// x_proj split-K reduce + dt-slice hi/lo emit.
// ---------------------------------------------------------------------------
__global__ __launch_bounds__(256) void add8_split(
    const float* __restrict__ p, float* __restrict__ o,
    bf16_t* __restrict__ dth, bf16_t* __restrict__ dtl,
    int n4, size_t stride4)
{
    const int i = blockIdx.x * 256 + threadIdx.x;
    if (i >= n4) return;
    float4 s = make_float4(0.f, 0.f, 0.f, 0.f);
#pragma unroll
    for (int k = 0; k < 8; ++k) {
        const float4 v = ((const float4*)p)[(size_t)k * stride4 + i];
        s.x += v.x; s.y += v.y; s.z += v.z; s.w += v.w;
    }
    ((float4*)o)[i] = s;

    const int col4 = i % 24;
    if (col4 < 16) {
        const int row = i / 24;
        const bf16_t h0 = (bf16_t)s.x, h1 = (bf16_t)s.y,
                     h2 = (bf16_t)s.z, h3 = (bf16_t)s.w;
        bf16x4 hv = {h0, h1, h2, h3};
        bf16x4 lv = {(bf16_t)(s.x - (float)h0), (bf16_t)(s.y - (float)h1),
                     (bf16_t)(s.z - (float)h2), (bf16_t)(s.w - (float)h3)};
        ((bf16x4*)dth)[(size_t)row * 16 + col4] = hv;
        ((bf16x4*)dtl)[(size_t)row * 16 + col4] = lv;
    }
}

// ---------------------------------------------------------------------------
// Fused in_proj (2-term): blockIdx.y < 16 -> x-half: Ah.Bh + Ah.Bl
//                         blockIdx.y >= 16 -> z-half: Ah.Bh (gate-only use)
// 128x128 tile, BK=32, 4 waves, mfma_f32_16x16x32_bf16.  LDS 24 KB.
// ---------------------------------------------------------------------------
__global__ __launch_bounds__(256) void in_proj_fused(
    const bf16_t* __restrict__ Ah,
    const bf16_t* __restrict__ Wh, const bf16_t* __restrict__ Wl,
    float* __restrict__ X, float* __restrict__ Z, int Ktot)
{
    __shared__ __align__(16) bf16_t Ash[128 * 32];
    __shared__ __align__(16) bf16_t Bsh[128 * 32];
    __shared__ __align__(16) bf16_t Bsl[128 * 32];

    const int tid  = threadIdx.x;
    const int lane = tid & 63;
    const int w    = tid >> 6;
    const int wr   = (w >> 1) * 64;
    const int wc   = (w & 1) * 64;
    const int bm   = blockIdx.x * 128;
    const int by   = blockIdx.y;
    const int l16  = lane & 15;
    const int lhi  = lane >> 4;

    f32x4 acc[4][4];
#pragma unroll
    for (int i = 0; i < 4; ++i)
#pragma unroll
        for (int j = 0; j < 4; ++j)
#pragma unroll
            for (int r = 0; r < 4; ++r) acc[i][j][r] = 0.f;

    const int srow0 = tid >> 2;
    const int sks   = (tid & 3) << 3;
    const int ldsb0 = tid * 16;

    if (by < 16) {
        const int bn = by * 128;
        for (int k0 = 0; k0 < Ktot; k0 += 32) {
            __syncthreads();
#pragma unroll
            for (int call = 0; call < 2; ++call) {
                const int row = srow0 + call * 64;
                const int wb  = ldsb0 + call * 4096;
                const size_t aoff = (size_t)(bm + row) * Ktot + k0 + sks;
                const size_t boff = (size_t)(bn + row) * Ktot + k0 + sks;
                GLOAD_LDS16(Ah + aoff, (char*)Ash + wb);
                GLOAD_LDS16(Wh + boff, (char*)Bsh + wb);
                GLOAD_LDS16(Wl + boff, (char*)Bsl + wb);
            }
            __syncthreads();

            bf16x8 ah[4], bh[4], bl[4];
#pragma unroll
            for (int f = 0; f < 4; ++f) {
                const int ar = (wr + f * 16 + l16) * 32 + lhi * 8;
                const int br = (wc + f * 16 + l16) * 32 + lhi * 8;
                ah[f] = *(const bf16x8*)&Ash[ar];
                bh[f] = *(const bf16x8*)&Bsh[br];
                bl[f] = *(const bf16x8*)&Bsl[br];
            }
#pragma unroll
            for (int fm = 0; fm < 4; ++fm)
#pragma unroll
                for (int fn = 0; fn < 4; ++fn) {
                    acc[fm][fn] = __builtin_amdgcn_mfma_f32_16x16x32_bf16(
                        ah[fm], bh[fn], acc[fm][fn], 0, 0, 0);
                    acc[fm][fn] = __builtin_amdgcn_mfma_f32_16x16x32_bf16(
                        ah[fm], bl[fn], acc[fm][fn], 0, 0, 0);
                }
        }
#pragma unroll
        for (int fm = 0; fm < 4; ++fm) {
            const int row0 = bm + wr + fm * 16 + lhi * 4;
#pragma unroll
            for (int fn = 0; fn < 4; ++fn) {
                const int col = bn + wc + fn * 16 + l16;
#pragma unroll
                for (int r = 0; r < 4; ++r)
                    X[(size_t)(row0 + r) * 2048 + col] = acc[fm][fn][r];
            }
        }
    } else {
        const int bnW = 2048 + (by - 16) * 128;
        const int bnC = (by - 16) * 128;
        for (int k0 = 0; k0 < Ktot; k0 += 32) {
            __syncthreads();
#pragma unroll
            for (int call = 0; call < 2; ++call) {
                const int row = srow0 + call * 64;
                const int wb  = ldsb0 + call * 4096;
                GLOAD_LDS16(Ah + (size_t)(bm + row) * Ktot + k0 + sks, (char*)Ash + wb);
                GLOAD_LDS16(Wh + (size_t)(bnW + row) * Ktot + k0 + sks, (char*)Bsh + wb);
            }
            __syncthreads();

            bf16x8 af[4], bfr[4];
#pragma unroll
            for (int f = 0; f < 4; ++f) {
                af[f]  = *(const bf16x8*)&Ash[(wr + f * 16 + l16) * 32 + lhi * 8];
                bfr[f] = *(const bf16x8*)&Bsh[(wc + f * 16 + l16) * 32 + lhi * 8];
            }
#pragma unroll
            for (int fm = 0; fm < 4; ++fm)
#pragma unroll
                for (int fn = 0; fn < 4; ++fn)
                    acc[fm][fn] = __builtin_amdgcn_mfma_f32_16x16x32_bf16(
                        af[fm], bfr[fn], acc[fm][fn], 0, 0, 0);
        }
#pragma unroll
        for (int fm = 0; fm < 4; ++fm) {
            const int row0 = bm + wr + fm * 16 + lhi * 4;
#pragma unroll
            for (int fn = 0; fn < 4; ++fn) {
                const int col = bnC + wc + fn * 16 + l16;
#pragma unroll
                for (int r = 0; r < 4; ++r)
                    Z[(size_t)(row0 + r) * 2048 + col] = acc[fm][fn][r];
            }
        }
    }
}

// ---------------------------------------------------------------------------
// Split-precision MFMA NT-GEMM (dt_proj).  128x128 tile, BK=32, 48 MFMA/step.
// EPI 2: v += bias[n]; softplus; store.
// ---------------------------------------------------------------------------
template<int EPI>
__global__ __launch_bounds__(256) void gemm_mfma3p(
    const bf16_t* __restrict__ Ah, const bf16_t* __restrict__ Al,
    const bf16_t* __restrict__ Bh, const bf16_t* __restrict__ Bl,
    float* __restrict__ C, const float* __restrict__ bias,
    int Ktot, int ldc)
{
    __shared__ __align__(16) bf16_t Ash[128 * 32];
    __shared__ __align__(16) bf16_t Asl[128 * 32];
    __shared__ __align__(16) bf16_t Bsh[128 * 32];
    __shared__ __align__(16) bf16_t Bsl[128 * 32];

    const int tid  = threadIdx.x;
    const int lane = tid & 63;
    const int w    = tid >> 6;
    const int wr   = (w >> 1) * 64;
    const int wc   = (w & 1) * 64;
    const int bm   = blockIdx.x * 128;
    const int bn   = blockIdx.y * 128;
    const int l16  = lane & 15;
    const int lhi  = lane >> 4;

    f32x4 acc[4][4];
#pragma unroll
    for (int i = 0; i < 4; ++i)
#pragma unroll
        for (int j = 0; j < 4; ++j)
#pragma unroll
            for (int r = 0; r < 4; ++r) acc[i][j][r] = 0.f;

    const int srow0 = tid >> 2;
    const int sks   = (tid & 3) << 3;
    const int ldsb0 = tid * 16;

    for (int k0 = 0; k0 < Ktot; k0 += 32) {
        __syncthreads();
#pragma unroll
        for (int call = 0; call < 2; ++call) {
            const int row = srow0 + call * 64;
            const int wb  = ldsb0 + call * 4096;
            const size_t aoff = (size_t)(bm + row) * Ktot + k0 + sks;
            const size_t boff = (size_t)(bn + row) * Ktot + k0 + sks;
            GLOAD_LDS16(Ah + aoff, (char*)Ash + wb);
            GLOAD_LDS16(Al + aoff, (char*)Asl + wb);
            GLOAD_LDS16(Bh + boff, (char*)Bsh + wb);
            GLOAD_LDS16(Bl + boff, (char*)Bsl + wb);
        }
        __syncthreads();

        bf16x8 ah[4], al[4], bh[4], bl[4];
#pragma unroll
        for (int f = 0; f < 4; ++f) {
            const int ar = (wr + f * 16 + l16) * 32 + lhi * 8;
            const int br = (wc + f * 16 + l16) * 32 + lhi * 8;
            ah[f] = *(const bf16x8*)&Ash[ar];
            al[f] = *(const bf16x8*)&Asl[ar];
            bh[f] = *(const bf16x8*)&Bsh[br];
            bl[f] = *(const bf16x8*)&Bsl[br];
        }
#pragma unroll
        for (int fm = 0; fm < 4; ++fm)
#pragma unroll
            for (int fn = 0; fn < 4; ++fn) {
                acc[fm][fn] = __builtin_amdgcn_mfma_f32_16x16x32_bf16(
                    ah[fm], bh[fn], acc[fm][fn], 0, 0, 0);
                acc[fm][fn] = __builtin_amdgcn_mfma_f32_16x16x32_bf16(
                    al[fm], bh[fn], acc[fm][fn], 0, 0, 0);
                acc[fm][fn] = __builtin_amdgcn_mfma_f32_16x16x32_bf16(
                    ah[fm], bl[fn], acc[fm][fn], 0, 0, 0);
            }
    }

#pragma unroll
    for (int fm = 0; fm < 4; ++fm) {
        const int row0 = bm + wr + fm * 16 + lhi * 4;
#pragma unroll
        for (int fn = 0; fn < 4; ++fn) {
            const int col = bn + wc + fn * 16 + l16;
#pragma unroll
            for (int r = 0; r < 4; ++r) {
                float v = acc[fm][fn][r];
                const size_t m = row0 + r;
                if (EPI == 2) {
                    v += bias[col];
                    v = (v > 20.f) ? v : log1pf(expf(v));
                }
                C[m * ldc + col] = v;
            }
        }
    }
}

// ---------------------------------------------------------------------------
// out_proj GEMM (2-term): C = Ah.Bh^T + Ah.Bl^T, A [M][K] fp32 reg-staged
// (bf16-hi only), B pre-split bf16 pair via global_load_lds.
// 64x128 tile, BK=32, 4 waves (2x2), 16 MFMA/k-step, 20 KB LDS.
// (R13 lesson: keep LDS <= ~24 KB; occupancy beats per-step amortization.)
// ---------------------------------------------------------------------------
__global__ __launch_bounds__(256) void gemm_mfma2o(
    const float* __restrict__ A,
    const bf16_t* __restrict__ Bh, const bf16_t* __restrict__ Bl,
    float* __restrict__ C, int K, int ldc)
{
    __shared__ __align__(16) bf16_t Ash[64 * 32];       // 4 KB
    __shared__ __align__(16) bf16_t Bsh[128 * 32];      // 8 KB
    __shared__ __align__(16) bf16_t Bsl[128 * 32];      // 8 KB

    const int tid  = threadIdx.x;
    const int lane = tid & 63;
    const int w    = tid >> 6;
    const int wr   = (w >> 1) * 32;
    const int wc   = (w & 1) * 64;
    const int bm   = blockIdx.x * 64;
    const int bn   = blockIdx.y * 128;
    const int l16  = lane & 15;
    const int lhi  = lane >> 4;

    f32x4 acc[2][4];
#pragma unroll
    for (int i = 0; i < 2; ++i)
#pragma unroll
        for (int j = 0; j < 4; ++j)
#pragma unroll
            for (int r = 0; r < 4; ++r) acc[i][j][r] = 0.f;

    const int srowA = tid >> 2;          // 0..63
    const int sks   = (tid & 3) << 3;    // 8-elem offset
    const int ldsb0 = tid * 16;

    for (int k0 = 0; k0 < K; k0 += 32) {
        __syncthreads();
        // B: 128 rows x 32 k, 2 gload calls, linear dest
#pragma unroll
        for (int call = 0; call < 2; ++call) {
            const int row = srowA + call * 64;
            const int wb  = ldsb0 + call * 4096;
            const size_t boff = (size_t)(bn + row) * K + k0 + sks;
            GLOAD_LDS16(Bh + boff, (char*)Bsh + wb);
            GLOAD_LDS16(Bl + boff, (char*)Bsl + wb);
        }
        // A: 64 rows fp32 -> bf16 hi, one ds_write per thread
        {
            const float* ap = A + (size_t)(bm + srowA) * K + k0 + sks;
            const float4 v0 = *(const float4*)ap;
            const float4 v1 = *(const float4*)(ap + 4);
            bf16x8 hv;
            hv[0] = (bf16_t)v0.x; hv[1] = (bf16_t)v0.y;
            hv[2] = (bf16_t)v0.z; hv[3] = (bf16_t)v0.w;
            hv[4] = (bf16_t)v1.x; hv[5] = (bf16_t)v1.y;
            hv[6] = (bf16_t)v1.z; hv[7] = (bf16_t)v1.w;
            *(bf16x8*)((char*)Ash + ldsb0) = hv;
        }
        __syncthreads();

        bf16x8 ah[2], bh[4], bl[4];
#pragma unroll
        for (int f = 0; f < 2; ++f)
            ah[f] = *(const bf16x8*)&Ash[(wr + f * 16 + l16) * 32 + lhi * 8];
#pragma unroll
        for (int f = 0; f < 4; ++f) {
            const int br = (wc + f * 16 + l16) * 32 + lhi * 8;
            bh[f] = *(const bf16x8*)&Bsh[br];
            bl[f] = *(const bf16x8*)&Bsl[br];
        }
#pragma unroll
        for (int fm = 0; fm < 2; ++fm)
#pragma unroll
            for (int fn = 0; fn < 4; ++fn) {
                acc[fm][fn] = __builtin_amdgcn_mfma_f32_16x16x32_bf16(
                    ah[fm], bh[fn], acc[fm][fn], 0, 0, 0);
                acc[fm][fn] = __builtin_amdgcn_mfma_f32_16x16x32_bf16(
                    ah[fm], bl[fn], acc[fm][fn], 0, 0, 0);
            }
    }

#pragma unroll
    for (int fm = 0; fm < 2; ++fm) {
        const int row0 = bm + wr + fm * 16 + lhi * 4;
#pragma unroll
        for (int fn = 0; fn < 4; ++fn) {
            const int col = bn + wc + fn * 16 + l16;
#pragma unroll
            for (int r = 0; r < 4; ++r)
                C[(size_t)(row0 + r) * ldc + col] = acc[fm][fn][r];
        }
    }
}

// ---------------------------------------------------------------------------
// Tiled fp32 NT-GEMM with split-K (x_proj).  64x64 tile.
// ---------------------------------------------------------------------------
__global__ __launch_bounds__(256) void gemm_nt_sk(
    const float* __restrict__ A, const float* __restrict__ B,
    float* __restrict__ C,
    int N, int Ksplit, int lda, int ldb, int ldc, size_t partStride)
{
    __shared__ float As[16][68];
    __shared__ float Bs[16][68];

    const int tid = threadIdx.x;
    const int tx = tid & 15;
    const int ty = tid >> 4;
    const int bm = blockIdx.x * 64;
    const int bn = blockIdx.y * 64;

    const int r  = tid >> 2;
    const int kc = (tid & 3) << 2;

    float acc[4][4];
#pragma unroll
    for (int i = 0; i < 4; ++i)
#pragma unroll
        for (int j = 0; j < 4; ++j) acc[i][j] = 0.f;

    const int kBeg = blockIdx.z * Ksplit;
    const int kEnd = kBeg + Ksplit;

    for (int k0 = kBeg; k0 < kEnd; k0 += 16) {
        float4 av = *(const float4*)(A + (size_t)(bm + r) * lda + k0 + kc);
        const int cB = bn + r;
        float4 bv = make_float4(0.f, 0.f, 0.f, 0.f);
        if (cB < N) bv = *(const float4*)(B + (size_t)cB * ldb + k0 + kc);

        As[kc + 0][r] = av.x; As[kc + 1][r] = av.y;
        As[kc + 2][r] = av.z; As[kc + 3][r] = av.w;
        Bs[kc + 0][r] = bv.x; Bs[kc + 1][r] = bv.y;
        Bs[kc + 2][r] = bv.z; Bs[kc + 3][r] = bv.w;
        __syncthreads();

#pragma unroll
        for (int kk = 0; kk < 16; ++kk) {
            float4 a4 = *(const float4*)&As[kk][ty << 2];
            float4 b4 = *(const float4*)&Bs[kk][tx << 2];
            float a[4] = {a4.x, a4.y, a4.z, a4.w};
            float b[4] = {b4.x, b4.y, b4.z, b4.w};
#pragma unroll
            for (int i = 0; i < 4; ++i)
#pragma unroll
                for (int j = 0; j < 4; ++j)
                    acc[i][j] = fmaf(a[i], b[j], acc[i][j]);
        }
        __syncthreads();
    }

    float* Cp = C + (size_t)blockIdx.z * partStride;
#pragma unroll
    for (int i = 0; i < 4; ++i) {
        const int m = bm + (ty << 2) + i;
#pragma unroll
        for (int j = 0; j < 4; ++j) {
            const int n = bn + (tx << 2) + j;
            if (n < N) Cp[(size_t)m * ldc + n] = acc[i][j];
        }
    }
}

// ---------------------------------------------------------------------------
// Depthwise causal conv (width 4) + bias + SiLU, 4 channels per thread.
// ---------------------------------------------------------------------------
__global__ __launch_bounds__(256) void conv_silu4(
    const float* __restrict__ xin, const float* __restrict__ w,
    const float* __restrict__ bias, float* __restrict__ xout,
    int L, int D)
{
    const long long e4 = (long long)blockIdx.x * 256 + threadIdx.x;
    const int Dq = D >> 2;
    const int dq = (int)(e4 % Dq);
    const long long bl = e4 / Dq;
    const int l = (int)(bl % L);
    const int d = dq << 2;
    const long long base = bl * D + d;

    const float4 zero = make_float4(0.f, 0.f, 0.f, 0.f);
    const float4 x0 = *(const float4*)&xin[base];
    const float4 x1 = (l >= 1) ? *(const float4*)&xin[base - D]     : zero;
    const float4 x2 = (l >= 2) ? *(const float4*)&xin[base - 2*D]   : zero;
    const float4 x3 = (l >= 3) ? *(const float4*)&xin[base - 3*D]   : zero;
    const float4 bv = *(const float4*)&bias[d];

    float4 out;
    {
        const float4 wv = *(const float4*)&w[(d + 0) * 4];
        float acc = bv.x;
        acc = fmaf(wv.w, x0.x, acc); acc = fmaf(wv.z, x1.x, acc);
        acc = fmaf(wv.y, x2.x, acc); acc = fmaf(wv.x, x3.x, acc);
        out.x = acc / (1.f + __expf(-acc));
    }
    {
        const float4 wv = *(const float4*)&w[(d + 1) * 4];
        float acc = bv.y;
        acc = fmaf(wv.w, x0.y, acc); acc = fmaf(wv.z, x1.y, acc);
        acc = fmaf(wv.y, x2.y, acc); acc = fmaf(wv.x, x3.y, acc);
        out.y = acc / (1.f + __expf(-acc));
    }
    {
        const float4 wv = *(const float4*)&w[(d + 2) * 4];
        float acc = bv.z;
        acc = fmaf(wv.w, x0.z, acc); acc = fmaf(wv.z, x1.z, acc);
        acc = fmaf(wv.y, x2.z, acc); acc = fmaf(wv.x, x3.z, acc);
        out.z = acc / (1.f + __expf(-acc));
    }
    {
        const float4 wv = *(const float4*)&w[(d + 3) * 4];
        float acc = bv.w;
        acc = fmaf(wv.w, x0.w, acc); acc = fmaf(wv.z, x1.w, acc);
        acc = fmaf(wv.y, x2.w, acc); acc = fmaf(wv.x, x3.w, acc);
        out.w = acc / (1.f + __expf(-acc));
    }
    *(float4*)&xout[base] = out;
}

// ---------------------------------------------------------------------------
// Scan pass 1 (per-channel): thread owns channel d, 16 states in registers.
// ---------------------------------------------------------------------------
__global__ __launch_bounds__(256) void scan_local2(
    const float* __restrict__ xconv, const float* __restrict__ dt,
    const float* __restrict__ xdbl,  const float* __restrict__ A_log,
    float* __restrict__ Sbuf, float* __restrict__ Pbuf)
{
    __shared__ float Bs[CH][16];

    const int d = blockIdx.x * 256 + threadIdx.x;
    const int c = blockIdx.y;
    const int b = blockIdx.z;
    const long long rowBase = (long long)b * 4096 + (long long)c * CH;

#pragma unroll
    for (int k = 0; k < 2; ++k) {
        const int e = k * 256 + threadIdx.x;
        const int i = e >> 2, j = (e & 3) << 2;
        *(float4*)&Bs[i][j] = *(const float4*)&xdbl[(rowBase + i) * 96 + 64 + j];
    }
    __syncthreads();

    float a[16], S[16];
#pragma unroll
    for (int n = 0; n < 16; ++n) {
        a[n] = -__expf(A_log[d * 16 + n]);
        S[n] = 0.f;
    }
    float sumdt = 0.f;

    for (int i = 0; i < CH; ++i) {
        const long long row = rowBase + i;
        const float dtv = dt[row * 2048 + d];
        const float xv  = xconv[row * 2048 + d];
        const float u   = dtv * xv;
        sumdt += dtv;
#pragma unroll
        for (int n = 0; n < 16; ++n) {
            const float dA = __expf(dtv * a[n]);
            S[n] = fmaf(S[n], dA, u * Bs[i][n]);
        }
    }

    const size_t base = ((((size_t)b * NC + c) * 2048) + d) * 16;
#pragma unroll
    for (int k = 0; k < 4; ++k) {
        *(float4*)&Sbuf[base + k * 4] =
            make_float4(S[k*4], S[k*4+1], S[k*4+2], S[k*4+3]);
        *(float4*)&Pbuf[base + k * 4] =
            make_float4(__expf(sumdt * a[k*4]),   __expf(sumdt * a[k*4+1]),
                        __expf(sumdt * a[k*4+2]), __expf(sumdt * a[k*4+3]));
    }
}

// ---------------------------------------------------------------------------
// Pass 2: sequential prefix over chunks; Sbuf becomes chunk-entering state.
// ---------------------------------------------------------------------------
__global__ __launch_bounds__(256) void scan_chunk_prefix(
    float* __restrict__ Sbuf, const float* __restrict__ Pbuf)
{
    const int tid = blockIdx.x * 256 + threadIdx.x;
    const int b  = tid >> 15;
    const int dn = tid & 32767;

    float H = 0.f;
    for (int c = 0; c < NC; ++c) {
        const size_t idx = ((size_t)b * NC + c) * 32768 + dn;
        const float S = Sbuf[idx];
        const float P = Pbuf[idx];
        Sbuf[idx] = H;
        H = fmaf(P, H, S);
    }
}

// ---------------------------------------------------------------------------
// Scan pass 3 (per-channel): seeded with H, gate, fp32 y in-place to xconv.
// ---------------------------------------------------------------------------
__global__ __launch_bounds__(256) void scan_final2(
    const float* __restrict__ xconv, const float* __restrict__ dt,
    const float* __restrict__ xdbl,  const float* __restrict__ A_log,
    const float* __restrict__ Dp,    const float* __restrict__ z,
    const float* __restrict__ Hbuf,  float* __restrict__ y)
{
    __shared__ float BCs[CH][32];    // [l][0..15]=B, [l][16..31]=C

    const int d = blockIdx.x * 256 + threadIdx.x;
    const int c = blockIdx.y;
    const int b = blockIdx.z;
    const long long rowBase = (long long)b * 4096 + (long long)c * CH;

#pragma unroll
    for (int k = 0; k < 4; ++k) {
        const int e = k * 256 + threadIdx.x;
        const int i = e >> 3, j = (e & 7) << 2;
        *(float4*)&BCs[i][j] = *(const float4*)&xdbl[(rowBase + i) * 96 + 64 + j];
    }
    __syncthreads();

    float a[16], h[16];
    const size_t hbase = ((((size_t)b * NC + c) * 2048) + d) * 16;
#pragma unroll
    for (int k = 0; k < 4; ++k) {
        const float4 hv = *(const float4*)&Hbuf[hbase + k * 4];
        h[k*4] = hv.x; h[k*4+1] = hv.y; h[k*4+2] = hv.z; h[k*4+3] = hv.w;
    }
#pragma unroll
    for (int n = 0; n < 16; ++n) a[n] = -__expf(A_log[d * 16 + n]);
    const float Dv = Dp[d];

    for (int i = 0; i < CH; ++i) {
        const long long row = rowBase + i;
        const float dtv = dt[row * 2048 + d];
        const float xv  = xconv[row * 2048 + d];
        const float u   = dtv * xv;
        float acc = 0.f;
#pragma unroll
        for (int n = 0; n < 16; ++n) {
            const float dA = __expf(dtv * a[n]);
            h[n] = fmaf(h[n], dA, u * BCs[i][n]);
            acc  = fmaf(h[n], BCs[i][16 + n], acc);
        }
        const float zv = z[row * 2048 + d];
        float yv = acc + xv * Dv;
        yv = yv * (zv / (1.f + __expf(-zv)));
        y[row * 2048 + d] = yv;
    }
}

// ---------------------------------------------------------------------------
extern "C" void kernel_launch(void* const* d_in, const int* in_sizes, int n_in,
                              void* d_out, int out_size, void* d_ws, size_t ws_size,
                              hipStream_t stream)
{
    const float* hidden     = (const float*)d_in[0];
    const float* in_proj_w  = (const float*)d_in[1];
    const float* conv_w     = (const float*)d_in[2];
    const float* conv_b     = (const float*)d_in[3];
    const float* x_proj_w   = (const float*)d_in[4];
    const float* dt_proj_w  = (const float*)d_in[5];
    const float* dt_proj_b  = (const float*)d_in[6];
    const float* A_log      = (const float*)d_in[7];
    const float* Dvec       = (const float*)d_in[8];
    const float* out_proj_w = (const float*)d_in[9];
    float* out = (float*)d_out;

    const int L = 4096, dinner = 2048, dmodel = 1024;
    const int M = 2 * L;  // 8192

    // ---- workspace layout: EXACTLY R2's proven 221.25 MB footprint ----
    float* z     = (float*)d_ws;                       // M*2048 fp32
    float* xraw  = z     + (size_t)M * dinner;         // M*2048 (x, xproj parts, dt)
    float* xconv = xraw  + (size_t)M * dinner;         // M*2048 (hid, xconv, y)
    float* xdbl  = xconv + (size_t)M * dinner;         // M*96
    float* Sbuf  = xdbl  + (size_t)M * 96;             // 2*NC*2048*16
    float* Pbuf  = Sbuf  + (size_t)2 * NC * dinner * 16;

    // lifetime-disjoint aliases (timeline):
    //  t0..in_proj : w1 pair = [Sbuf .. Pbuf end) 16.78 MB; hid_h in xconv
    //  post-in_proj: dth/dtl in Sbuf+0..2MB (add8_split), wd pair at +2MB
    //                (w1 dead); all dead before scan_local2 writes Sbuf/Pbuf.
    bf16_t* w1_h  = (bf16_t*)Sbuf;
    bf16_t* w1_l  = w1_h + (size_t)2 * dinner * dmodel;
    bf16_t* hid_h = (bf16_t*)xconv;                    // hi only (2-term in_proj)
    float*  xp_part = xraw;
    bf16_t* dth  = (bf16_t*)Sbuf;                      // [M][64] x2 = 2 MB
    bf16_t* dtl  = dth + (size_t)M * 64;
    bf16_t* wdh  = dtl + (size_t)M * 64;               // [2048][64] x2 = 0.5 MB
    bf16_t* wdl  = wdh + (size_t)dinner * 64;
    bf16_t* w2_h  = (bf16_t*)z;                        // split after scan consumed z
    bf16_t* w2_l  = w2_h + (size_t)dmodel * dinner;

    // ---- 0. fused t=0 splits: hidden (hi only) + in_proj_w (pair) ----
    const int n4a = M * dmodel / 4;
    const int n4b = 2 * dinner * dmodel / 4;
    split2m<<<(n4a + n4b + 255) / 256, 256, 0, stream>>>(
        hidden, hid_h, n4a,
        in_proj_w, w1_h, w1_l, n4b);

    // ---- 1. in_proj fused (x-half 2-term | z-half 1-term) ----
    in_proj_fused<<<dim3(M / 128, 32), 256, 0, stream>>>(
        hid_h, w1_h, w1_l, xraw, z, dmodel);

    // ---- 1b. split dt_proj_w (w1 now dead) ----
    split_hl<<<(dinner * 64 / 4 + 255) / 256, 256, 0, stream>>>(
        dt_proj_w, wdh, wdl, dinner * 64 / 4);

    // ---- 2. depthwise conv + bias + SiLU (x4 vectorized) ----
    conv_silu4<<<(M * (long long)dinner / 4) / 256, 256, 0, stream>>>(
        xraw, conv_w, conv_b, xconv, L, dinner);

    // ---- 3. x_proj (fp32, split-K=8): partials -> add8_split -> xdbl ----
    gemm_nt_sk<<<dim3(M / 64, 2, 8), 256, 0, stream>>>(
        xconv, x_proj_w, xp_part, 96, 2048 / 8, 2048, 2048, 96,
        (size_t)M * 96);
    add8_split<<<(M * 96 / 4 + 255) / 256, 256, 0, stream>>>(
        xp_part, xdbl, dth, dtl, M * 96 / 4, (size_t)M * 96 / 4);

    // ---- 4. dt_proj (3-term MFMA, K=64): softplus(dt@W^T + b) -> xraw ----
    gemm_mfma3p<2><<<dim3(M / 128, 2048 / 128), 256, 0, stream>>>(
        dth, dtl, wdh, wdl, xraw, dt_proj_b, 64, 2048);

    // ---- 5. chunked selective scan (per-channel register-state form) ----
    scan_local2<<<dim3(dinner / 256, NC, 2), 256, 0, stream>>>(
        xconv, xraw, xdbl, A_log, Sbuf, Pbuf);
    scan_chunk_prefix<<<256, 256, 0, stream>>>(Sbuf, Pbuf);
    scan_final2<<<dim3(dinner / 256, NC, 2), 256, 0, stream>>>(
        xconv, xraw, xdbl, A_log, Dvec, z, Sbuf, xconv);

    // ---- 5b. split out_proj_w into bf16 hi/lo (into z region, now dead) ----
    split_hl<<<(dmodel * dinner / 4 + 255) / 256, 256, 0, stream>>>(
        out_proj_w, w2_h, w2_l, dmodel * dinner / 4);

    // ---- 6. out_proj (2-term, BK=32, 20 KB LDS): A=y fp32 -> out ----
    gemm_mfma2o<<<dim3(M / 64, 1024 / 128), 256, 0, stream>>>(
        xconv, w2_h, w2_l, out, dinner, 1024);
}

// Round 15
// 581.492 us; speedup vs baseline: 1.1910x; 1.1051x over previous
//
#include <hip/hip_runtime.h>
#include <cmath>

#define CH 128          // scan chunk length
#define NC 32           // 4096 / CH

typedef __bf16 bf16_t;
typedef __attribute__((ext_vector_type(8))) __bf16 bf16x8;
typedef __attribute__((ext_vector_type(4))) __bf16 bf16x4;
typedef __attribute__((ext_vector_type(4))) float f32x4;

// CK idiom: generic->AS1/AS3 via uintptr for global_load_lds (width 16).
// NOTE (m104): LDS dest must be LINEAR in lane order (base + lane*16).
#define GLOAD_LDS16(gp, lp)                                                     \
    __builtin_amdgcn_global_load_lds(                                           \
        (const __attribute__((address_space(1))) unsigned int*)(uintptr_t)(gp), \
        (__attribute__((address_space(3))) unsigned int*)(uintptr_t)(lp),       \
        16, 0, 0)

// ---------------------------------------------------------------------------
// fp32 -> (hi, lo) bf16 split.  4 floats per thread.  (w2)
// ---------------------------------------------------------------------------
__global__ __launch_bounds__(256) void split_hl(
    const float* __restrict__ in, bf16_t* __restrict__ hi,
    bf16_t* __restrict__ lo, int n4)
{
    const int i = blockIdx.x * 256 + threadIdx.x;
    if (i >= n4) return;
    const float4 v = ((const float4*)in)[i];
    const bf16_t h0 = (bf16_t)v.x, h1 = (bf16_t)v.y,
                 h2 = (bf16_t)v.z, h3 = (bf16_t)v.w;
    bf16x4 hv = {h0, h1, h2, h3};
    bf16x4 lv = {(bf16_t)(v.x - (float)h0), (bf16_t)(v.y - (float)h1),
                 (bf16_t)(v.z - (float)h2), (bf16_t)(v.w - (float)h3)};
    ((bf16x4*)hi)[i] = hv;
    ((bf16x4*)lo)[i] = lv;
}

// ---------------------------------------------------------------------------
// t=0: hidden -> hi only; in_proj_w -> hi/lo pair.
// ---------------------------------------------------------------------------
__global__ __launch_bounds__(256) void split2m(
    const float* __restrict__ a, bf16_t* __restrict__ ah, int n4a,
    const float* __restrict__ b, bf16_t* __restrict__ bh, bf16_t* __restrict__ bl, int n4b)
{
    const int i = blockIdx.x * 256 + threadIdx.x;
    if (i < n4a) {
        const float4 v = ((const float4*)a)[i];
        bf16x4 hv = {(bf16_t)v.x, (bf16_t)v.y, (bf16_t)v.z, (bf16_t)v.w};
        ((bf16x4*)ah)[i] = hv;
    } else if (i < n4a + n4b) {
        const int j = i - n4a;
        const float4 v = ((const float4*)b)[j];
        const bf16_t h0 = (bf16_t)v.x, h1 = (bf16_t)v.y,
                     h2 = (bf16_t)v.z, h3 = (bf16_t)v.w;
        bf16x4 hv = {h0, h1, h2, h3};
        bf16x4 lv = {(bf16_t)(v.x - (float)h0), (bf16_t)(v.y - (float)h1),
                     (bf16_t)(v.z - (float)h2), (bf16_t)(v.w - (float)h3)};
        ((bf16x4*)bh)[j] = hv;
        ((bf16x4*)bl)[j] = lv;
    }
}

// ---------------------------------------------------------------------------
// post-in_proj: dt_proj_w -> pair; x_proj_w -> pair.  One launch.
// ---------------------------------------------------------------------------
__global__ __launch_bounds__(256) void split2w(
    const float* __restrict__ a, bf16_t* __restrict__ ah, bf16_t* __restrict__ al, int n4a,
    const float* __restrict__ b, bf16_t* __restrict__ bh, bf16_t* __restrict__ bl, int n4b)
{
    const int i = blockIdx.x * 256 + threadIdx.x;
    const float* src; bf16_t* hp; bf16_t* lp; int j;
    if (i < n4a)            { src = a; hp = ah; lp = al; j = i; }
    else if (i < n4a + n4b) { src = b; hp = bh; lp = bl; j = i - n4a; }
    else return;
    const float4 v = ((const float4*)src)[j];
    const bf16_t h0 = (bf16_t)v.x, h1 = (bf16_t)v.y,
                 h2 = (bf16_t)v.z, h3 = (bf16_t)v.w;
    bf16x4 hv = {h0, h1, h2, h3};
    bf16x4 lv = {(bf16_t)(v.x - (float)h0), (bf16_t)(v.y - (float)h1),
                 (bf16_t)(v.z - (float)h2), (bf16_t)(v.w - (float)h3)};
    ((bf16x4*)hp)[j] = hv;
    ((bf16x4*)lp)[j] = lv;
}

// ---------------------------------------------------------------------------
// x_proj split-K reduce + dt-slice hi/lo emit.
// ---------------------------------------------------------------------------
__global__ __launch_bounds__(256) void add8_split(
    const float* __restrict__ p, float* __restrict__ o,
    bf16_t* __restrict__ dth, bf16_t* __restrict__ dtl,
    int n4, size_t stride4)
{
    const int i = blockIdx.x * 256 + threadIdx.x;
    if (i >= n4) return;
    float4 s = make_float4(0.f, 0.f, 0.f, 0.f);
#pragma unroll
    for (int k = 0; k < 8; ++k) {
        const float4 v = ((const float4*)p)[(size_t)k * stride4 + i];
        s.x += v.x; s.y += v.y; s.z += v.z; s.w += v.w;
    }
    ((float4*)o)[i] = s;

    const int col4 = i % 24;
    if (col4 < 16) {
        const int row = i / 24;
        const bf16_t h0 = (bf16_t)s.x, h1 = (bf16_t)s.y,
                     h2 = (bf16_t)s.z, h3 = (bf16_t)s.w;
        bf16x4 hv = {h0, h1, h2, h3};
        bf16x4 lv = {(bf16_t)(s.x - (float)h0), (bf16_t)(s.y - (float)h1),
                     (bf16_t)(s.z - (float)h2), (bf16_t)(s.w - (float)h3)};
        ((bf16x4*)dth)[(size_t)row * 16 + col4] = hv;
        ((bf16x4*)dtl)[(size_t)row * 16 + col4] = lv;
    }
}

// ---------------------------------------------------------------------------
// Fused in_proj (2-term x | 1-term z).  128x128, BK=32, 24 KB LDS.
// ---------------------------------------------------------------------------
__global__ __launch_bounds__(256) void in_proj_fused(
    const bf16_t* __restrict__ Ah,
    const bf16_t* __restrict__ Wh, const bf16_t* __restrict__ Wl,
    float* __restrict__ X, float* __restrict__ Z, int Ktot)
{
    __shared__ __align__(16) bf16_t Ash[128 * 32];
    __shared__ __align__(16) bf16_t Bsh[128 * 32];
    __shared__ __align__(16) bf16_t Bsl[128 * 32];

    const int tid  = threadIdx.x;
    const int lane = tid & 63;
    const int w    = tid >> 6;
    const int wr   = (w >> 1) * 64;
    const int wc   = (w & 1) * 64;
    const int bm   = blockIdx.x * 128;
    const int by   = blockIdx.y;
    const int l16  = lane & 15;
    const int lhi  = lane >> 4;

    f32x4 acc[4][4];
#pragma unroll
    for (int i = 0; i < 4; ++i)
#pragma unroll
        for (int j = 0; j < 4; ++j)
#pragma unroll
            for (int r = 0; r < 4; ++r) acc[i][j][r] = 0.f;

    const int srow0 = tid >> 2;
    const int sks   = (tid & 3) << 3;
    const int ldsb0 = tid * 16;

    if (by < 16) {
        const int bn = by * 128;
        for (int k0 = 0; k0 < Ktot; k0 += 32) {
            __syncthreads();
#pragma unroll
            for (int call = 0; call < 2; ++call) {
                const int row = srow0 + call * 64;
                const int wb  = ldsb0 + call * 4096;
                const size_t aoff = (size_t)(bm + row) * Ktot + k0 + sks;
                const size_t boff = (size_t)(bn + row) * Ktot + k0 + sks;
                GLOAD_LDS16(Ah + aoff, (char*)Ash + wb);
                GLOAD_LDS16(Wh + boff, (char*)Bsh + wb);
                GLOAD_LDS16(Wl + boff, (char*)Bsl + wb);
            }
            __syncthreads();

            bf16x8 ah[4], bh[4], bl[4];
#pragma unroll
            for (int f = 0; f < 4; ++f) {
                const int ar = (wr + f * 16 + l16) * 32 + lhi * 8;
                const int br = (wc + f * 16 + l16) * 32 + lhi * 8;
                ah[f] = *(const bf16x8*)&Ash[ar];
                bh[f] = *(const bf16x8*)&Bsh[br];
                bl[f] = *(const bf16x8*)&Bsl[br];
            }
#pragma unroll
            for (int fm = 0; fm < 4; ++fm)
#pragma unroll
                for (int fn = 0; fn < 4; ++fn) {
                    acc[fm][fn] = __builtin_amdgcn_mfma_f32_16x16x32_bf16(
                        ah[fm], bh[fn], acc[fm][fn], 0, 0, 0);
                    acc[fm][fn] = __builtin_amdgcn_mfma_f32_16x16x32_bf16(
                        ah[fm], bl[fn], acc[fm][fn], 0, 0, 0);
                }
        }
#pragma unroll
        for (int fm = 0; fm < 4; ++fm) {
            const int row0 = bm + wr + fm * 16 + lhi * 4;
#pragma unroll
            for (int fn = 0; fn < 4; ++fn) {
                const int col = bn + wc + fn * 16 + l16;
#pragma unroll
                for (int r = 0; r < 4; ++r)
                    X[(size_t)(row0 + r) * 2048 + col] = acc[fm][fn][r];
            }
        }
    } else {
        const int bnW = 2048 + (by - 16) * 128;
        const int bnC = (by - 16) * 128;
        for (int k0 = 0; k0 < Ktot; k0 += 32) {
            __syncthreads();
#pragma unroll
            for (int call = 0; call < 2; ++call) {
                const int row = srow0 + call * 64;
                const int wb  = ldsb0 + call * 4096;
                GLOAD_LDS16(Ah + (size_t)(bm + row) * Ktot + k0 + sks, (char*)Ash + wb);
                GLOAD_LDS16(Wh + (size_t)(bnW + row) * Ktot + k0 + sks, (char*)Bsh + wb);
            }
            __syncthreads();

            bf16x8 af[4], bfr[4];
#pragma unroll
            for (int f = 0; f < 4; ++f) {
                af[f]  = *(const bf16x8*)&Ash[(wr + f * 16 + l16) * 32 + lhi * 8];
                bfr[f] = *(const bf16x8*)&Bsh[(wc + f * 16 + l16) * 32 + lhi * 8];
            }
#pragma unroll
            for (int fm = 0; fm < 4; ++fm)
#pragma unroll
                for (int fn = 0; fn < 4; ++fn)
                    acc[fm][fn] = __builtin_amdgcn_mfma_f32_16x16x32_bf16(
                        af[fm], bfr[fn], acc[fm][fn], 0, 0, 0);
        }
#pragma unroll
        for (int fm = 0; fm < 4; ++fm) {
            const int row0 = bm + wr + fm * 16 + lhi * 4;
#pragma unroll
            for (int fn = 0; fn < 4; ++fn) {
                const int col = bnC + wc + fn * 16 + l16;
#pragma unroll
                for (int r = 0; r < 4; ++r)
                    Z[(size_t)(row0 + r) * 2048 + col] = acc[fm][fn][r];
            }
        }
    }
}

// ---------------------------------------------------------------------------
// Split-precision MFMA NT-GEMM (dt_proj).  128x128 tile, BK=32, 48 MFMA/step.
// EPI 2: v += bias[n]; softplus; store.
// ---------------------------------------------------------------------------
template<int EPI>
__global__ __launch_bounds__(256) void gemm_mfma3p(
    const bf16_t* __restrict__ Ah, const bf16_t* __restrict__ Al,
    const bf16_t* __restrict__ Bh, const bf16_t* __restrict__ Bl,
    float* __restrict__ C, const float* __restrict__ bias,
    int Ktot, int ldc)
{
    __shared__ __align__(16) bf16_t Ash[128 * 32];
    __shared__ __align__(16) bf16_t Asl[128 * 32];
    __shared__ __align__(16) bf16_t Bsh[128 * 32];
    __shared__ __align__(16) bf16_t Bsl[128 * 32];

    const int tid  = threadIdx.x;
    const int lane = tid & 63;
    const int w    = tid >> 6;
    const int wr   = (w >> 1) * 64;
    const int wc   = (w & 1) * 64;
    const int bm   = blockIdx.x * 128;
    const int bn   = blockIdx.y * 128;
    const int l16  = lane & 15;
    const int lhi  = lane >> 4;

    f32x4 acc[4][4];
#pragma unroll
    for (int i = 0; i < 4; ++i)
#pragma unroll
        for (int j = 0; j < 4; ++j)
#pragma unroll
            for (int r = 0; r < 4; ++r) acc[i][j][r] = 0.f;

    const int srow0 = tid >> 2;
    const int sks   = (tid & 3) << 3;
    const int ldsb0 = tid * 16;

    for (int k0 = 0; k0 < Ktot; k0 += 32) {
        __syncthreads();
#pragma unroll
        for (int call = 0; call < 2; ++call) {
            const int row = srow0 + call * 64;
            const int wb  = ldsb0 + call * 4096;
            const size_t aoff = (size_t)(bm + row) * Ktot + k0 + sks;
            const size_t boff = (size_t)(bn + row) * Ktot + k0 + sks;
            GLOAD_LDS16(Ah + aoff, (char*)Ash + wb);
            GLOAD_LDS16(Al + aoff, (char*)Asl + wb);
            GLOAD_LDS16(Bh + boff, (char*)Bsh + wb);
            GLOAD_LDS16(Bl + boff, (char*)Bsl + wb);
        }
        __syncthreads();

        bf16x8 ah[4], al[4], bh[4], bl[4];
#pragma unroll
        for (int f = 0; f < 4; ++f) {
            const int ar = (wr + f * 16 + l16) * 32 + lhi * 8;
            const int br = (wc + f * 16 + l16) * 32 + lhi * 8;
            ah[f] = *(const bf16x8*)&Ash[ar];
            al[f] = *(const bf16x8*)&Asl[ar];
            bh[f] = *(const bf16x8*)&Bsh[br];
            bl[f] = *(const bf16x8*)&Bsl[br];
        }
#pragma unroll
        for (int fm = 0; fm < 4; ++fm)
#pragma unroll
            for (int fn = 0; fn < 4; ++fn) {
                acc[fm][fn] = __builtin_amdgcn_mfma_f32_16x16x32_bf16(
                    ah[fm], bh[fn], acc[fm][fn], 0, 0, 0);
                acc[fm][fn] = __builtin_amdgcn_mfma_f32_16x16x32_bf16(
                    al[fm], bh[fn], acc[fm][fn], 0, 0, 0);
                acc[fm][fn] = __builtin_amdgcn_mfma_f32_16x16x32_bf16(
                    ah[fm], bl[fn], acc[fm][fn], 0, 0, 0);
            }
    }

#pragma unroll
    for (int fm = 0; fm < 4; ++fm) {
        const int row0 = bm + wr + fm * 16 + lhi * 4;
#pragma unroll
        for (int fn = 0; fn < 4; ++fn) {
            const int col = bn + wc + fn * 16 + l16;
#pragma unroll
            for (int r = 0; r < 4; ++r) {
                float v = acc[fm][fn][r];
                const size_t m = row0 + r;
                if (EPI == 2) {
                    v += bias[col];
                    v = (v > 20.f) ? v : log1pf(expf(v));
                }
                C[m * ldc + col] = v;
            }
        }
    }
}

// ---------------------------------------------------------------------------
// x_proj, 3-term MFMA, split-K.  A = xconv bf16 pair, B = x_proj_w pair
// (96 rows; staging rows clamped to 95, cols >= 96 not stored).
// 128x(128) tile, BK=32, 48 MFMA/step; partial -> C + z*partStride (ldc=96).
// ---------------------------------------------------------------------------
__global__ __launch_bounds__(256) void gemm_mfma3x(
    const bf16_t* __restrict__ Ah, const bf16_t* __restrict__ Al,
    const bf16_t* __restrict__ Bh, const bf16_t* __restrict__ Bl,
    float* __restrict__ C, int Ktot, int Ksplit, size_t partStride)
{
    __shared__ __align__(16) bf16_t Ash[128 * 32];
    __shared__ __align__(16) bf16_t Asl[128 * 32];
    __shared__ __align__(16) bf16_t Bsh[128 * 32];
    __shared__ __align__(16) bf16_t Bsl[128 * 32];

    const int tid  = threadIdx.x;
    const int lane = tid & 63;
    const int w    = tid >> 6;
    const int wr   = (w >> 1) * 64;
    const int wc   = (w & 1) * 64;
    const int bm   = blockIdx.x * 128;
    const int l16  = lane & 15;
    const int lhi  = lane >> 4;

    f32x4 acc[4][4];
#pragma unroll
    for (int i = 0; i < 4; ++i)
#pragma unroll
        for (int j = 0; j < 4; ++j)
#pragma unroll
            for (int r = 0; r < 4; ++r) acc[i][j][r] = 0.f;

    const int srow0 = tid >> 2;
    const int sks   = (tid & 3) << 3;
    const int ldsb0 = tid * 16;

    const int kBeg = blockIdx.z * Ksplit;
    const int kEnd = kBeg + Ksplit;

    for (int k0 = kBeg; k0 < kEnd; k0 += 32) {
        __syncthreads();
#pragma unroll
        for (int call = 0; call < 2; ++call) {
            const int row  = srow0 + call * 64;
            const int brow = (row < 96) ? row : 95;     // clamp (in-bounds read)
            const int wb   = ldsb0 + call * 4096;
            const size_t aoff = (size_t)(bm + row) * Ktot + k0 + sks;
            const size_t boff = (size_t)brow * Ktot + k0 + sks;
            GLOAD_LDS16(Ah + aoff, (char*)Ash + wb);
            GLOAD_LDS16(Al + aoff, (char*)Asl + wb);
            GLOAD_LDS16(Bh + boff, (char*)Bsh + wb);
            GLOAD_LDS16(Bl + boff, (char*)Bsl + wb);
        }
        __syncthreads();

        bf16x8 ah[4], al[4], bh[4], bl[4];
#pragma unroll
        for (int f = 0; f < 4; ++f) {
            const int ar = (wr + f * 16 + l16) * 32 + lhi * 8;
            const int br = (wc + f * 16 + l16) * 32 + lhi * 8;
            ah[f] = *(const bf16x8*)&Ash[ar];
            al[f] = *(const bf16x8*)&Asl[ar];
            bh[f] = *(const bf16x8*)&Bsh[br];
            bl[f] = *(const bf16x8*)&Bsl[br];
        }
#pragma unroll
        for (int fm = 0; fm < 4; ++fm)
#pragma unroll
            for (int fn = 0; fn < 4; ++fn) {
                acc[fm][fn] = __builtin_amdgcn_mfma_f32_16x16x32_bf16(
                    ah[fm], bh[fn], acc[fm][fn], 0, 0, 0);
                acc[fm][fn] = __builtin_amdgcn_mfma_f32_16x16x32_bf16(
                    al[fm], bh[fn], acc[fm][fn], 0, 0, 0);
                acc[fm][fn] = __builtin_amdgcn_mfma_f32_16x16x32_bf16(
                    ah[fm], bl[fn], acc[fm][fn], 0, 0, 0);
            }
    }

    float* Cp = C + (size_t)blockIdx.z * partStride;
#pragma unroll
    for (int fm = 0; fm < 4; ++fm) {
        const int row0 = bm + wr + fm * 16 + lhi * 4;
#pragma unroll
        for (int fn = 0; fn < 4; ++fn) {
            const int col = wc + fn * 16 + l16;
            if (col < 96) {
#pragma unroll
                for (int r = 0; r < 4; ++r)
                    Cp[(size_t)(row0 + r) * 96 + col] = acc[fm][fn][r];
            }
        }
    }
}

// ---------------------------------------------------------------------------
// out_proj (2-term, pure bf16 staging): C = Ah.Bh^T + Ah.Bl^T.
// A = y bf16 [M][K] via global_load_lds; B pair via global_load_lds.
// 64x128 tile, BK=32, 4 waves (2x2), 16 MFMA/k-step, 20 KB LDS.
// ---------------------------------------------------------------------------
__global__ __launch_bounds__(256) void gemm_mfma2ob(
    const bf16_t* __restrict__ Ah,
    const bf16_t* __restrict__ Bh, const bf16_t* __restrict__ Bl,
    float* __restrict__ C, int K, int ldc)
{
    __shared__ __align__(16) bf16_t Ash[64 * 32];       // 4 KB
    __shared__ __align__(16) bf16_t Bsh[128 * 32];      // 8 KB
    __shared__ __align__(16) bf16_t Bsl[128 * 32];      // 8 KB

    const int tid  = threadIdx.x;
    const int lane = tid & 63;
    const int w    = tid >> 6;
    const int wr   = (w >> 1) * 32;
    const int wc   = (w & 1) * 64;
    const int bm   = blockIdx.x * 64;
    const int bn   = blockIdx.y * 128;
    const int l16  = lane & 15;
    const int lhi  = lane >> 4;

    f32x4 acc[2][4];
#pragma unroll
    for (int i = 0; i < 2; ++i)
#pragma unroll
        for (int j = 0; j < 4; ++j)
#pragma unroll
            for (int r = 0; r < 4; ++r) acc[i][j][r] = 0.f;

    const int srow = tid >> 2;
    const int sks  = (tid & 3) << 3;
    const int ldsb0 = tid * 16;

    for (int k0 = 0; k0 < K; k0 += 32) {
        __syncthreads();
        // A: 64 rows, 1 call, linear dest
        GLOAD_LDS16(Ah + (size_t)(bm + srow) * K + k0 + sks, (char*)Ash + ldsb0);
        // B: 128 rows, 2 calls
#pragma unroll
        for (int call = 0; call < 2; ++call) {
            const int row = srow + call * 64;
            const int wb  = ldsb0 + call * 4096;
            const size_t boff = (size_t)(bn + row) * K + k0 + sks;
            GLOAD_LDS16(Bh + boff, (char*)Bsh + wb);
            GLOAD_LDS16(Bl + boff, (char*)Bsl + wb);
        }
        __syncthreads();

        bf16x8 ah[2], bh[4], bl[4];
#pragma unroll
        for (int f = 0; f < 2; ++f)
            ah[f] = *(const bf16x8*)&Ash[(wr + f * 16 + l16) * 32 + lhi * 8];
#pragma unroll
        for (int f = 0; f < 4; ++f) {
            const int br = (wc + f * 16 + l16) * 32 + lhi * 8;
            bh[f] = *(const bf16x8*)&Bsh[br];
            bl[f] = *(const bf16x8*)&Bsl[br];
        }
#pragma unroll
        for (int fm = 0; fm < 2; ++fm)
#pragma unroll
            for (int fn = 0; fn < 4; ++fn) {
                acc[fm][fn] = __builtin_amdgcn_mfma_f32_16x16x32_bf16(
                    ah[fm], bh[fn], acc[fm][fn], 0, 0, 0);
                acc[fm][fn] = __builtin_amdgcn_mfma_f32_16x16x32_bf16(
                    ah[fm], bl[fn], acc[fm][fn], 0, 0, 0);
            }
    }

#pragma unroll
    for (int fm = 0; fm < 2; ++fm) {
        const int row0 = bm + wr + fm * 16 + lhi * 4;
#pragma unroll
        for (int fn = 0; fn < 4; ++fn) {
            const int col = bn + wc + fn * 16 + l16;
#pragma unroll
            for (int r = 0; r < 4; ++r)
                C[(size_t)(row0 + r) * ldc + col] = acc[fm][fn][r];
        }
    }
}

// ---------------------------------------------------------------------------
// Depthwise causal conv (width 4) + bias + SiLU -> bf16 hi/lo pair.
// ---------------------------------------------------------------------------
__global__ __launch_bounds__(256) void conv_silu4b(
    const float* __restrict__ xin, const float* __restrict__ w,
    const float* __restrict__ bias,
    bf16_t* __restrict__ xh, bf16_t* __restrict__ xl,
    int L, int D)
{
    const long long e4 = (long long)blockIdx.x * 256 + threadIdx.x;
    const int Dq = D >> 2;
    const int dq = (int)(e4 % Dq);
    const long long bl = e4 / Dq;
    const int l = (int)(bl % L);
    const int d = dq << 2;
    const long long base = bl * D + d;

    const float4 zero = make_float4(0.f, 0.f, 0.f, 0.f);
    const float4 x0 = *(const float4*)&xin[base];
    const float4 x1 = (l >= 1) ? *(const float4*)&xin[base - D]     : zero;
    const float4 x2 = (l >= 2) ? *(const float4*)&xin[base - 2*D]   : zero;
    const float4 x3 = (l >= 3) ? *(const float4*)&xin[base - 3*D]   : zero;
    const float4 bv = *(const float4*)&bias[d];

    float o[4];
    {
        const float4 wv = *(const float4*)&w[(d + 0) * 4];
        float acc = bv.x;
        acc = fmaf(wv.w, x0.x, acc); acc = fmaf(wv.z, x1.x, acc);
        acc = fmaf(wv.y, x2.x, acc); acc = fmaf(wv.x, x3.x, acc);
        o[0] = acc / (1.f + __expf(-acc));
    }
    {
        const float4 wv = *(const float4*)&w[(d + 1) * 4];
        float acc = bv.y;
        acc = fmaf(wv.w, x0.y, acc); acc = fmaf(wv.z, x1.y, acc);
        acc = fmaf(wv.y, x2.y, acc); acc = fmaf(wv.x, x3.y, acc);
        o[1] = acc / (1.f + __expf(-acc));
    }
    {
        const float4 wv = *(const float4*)&w[(d + 2) * 4];
        float acc = bv.z;
        acc = fmaf(wv.w, x0.z, acc); acc = fmaf(wv.z, x1.z, acc);
        acc = fmaf(wv.y, x2.z, acc); acc = fmaf(wv.x, x3.z, acc);
        o[2] = acc / (1.f + __expf(-acc));
    }
    {
        const float4 wv = *(const float4*)&w[(d + 3) * 4];
        float acc = bv.w;
        acc = fmaf(wv.w, x0.w, acc); acc = fmaf(wv.z, x1.w, acc);
        acc = fmaf(wv.y, x2.w, acc); acc = fmaf(wv.x, x3.w, acc);
        o[3] = acc / (1.f + __expf(-acc));
    }
    bf16x4 hv, lv;
#pragma unroll
    for (int e = 0; e < 4; ++e) {
        const bf16_t h = (bf16_t)o[e];
        hv[e] = h;
        lv[e] = (bf16_t)(o[e] - (float)h);
    }
    *(bf16x4*)&xh[base] = hv;
    *(bf16x4*)&xl[base] = lv;
}

// ---------------------------------------------------------------------------
// Scan pass 1 (per-channel): xconv read as bf16 pair.
// ---------------------------------------------------------------------------
__global__ __launch_bounds__(256) void scan_local2(
    const bf16_t* __restrict__ xh, const bf16_t* __restrict__ xl,
    const float* __restrict__ dt,
    const float* __restrict__ xdbl,  const float* __restrict__ A_log,
    float* __restrict__ Sbuf, float* __restrict__ Pbuf)
{
    __shared__ float Bs[CH][16];

    const int d = blockIdx.x * 256 + threadIdx.x;
    const int c = blockIdx.y;
    const int b = blockIdx.z;
    const long long rowBase = (long long)b * 4096 + (long long)c * CH;

#pragma unroll
    for (int k = 0; k < 2; ++k) {
        const int e = k * 256 + threadIdx.x;
        const int i = e >> 2, j = (e & 3) << 2;
        *(float4*)&Bs[i][j] = *(const float4*)&xdbl[(rowBase + i) * 96 + 64 + j];
    }
    __syncthreads();

    float a[16], S[16];
#pragma unroll
    for (int n = 0; n < 16; ++n) {
        a[n] = -__expf(A_log[d * 16 + n]);
        S[n] = 0.f;
    }
    float sumdt = 0.f;

    for (int i = 0; i < CH; ++i) {
        const long long row = rowBase + i;
        const float dtv = dt[row * 2048 + d];
        const float xv  = (float)xh[row * 2048 + d] + (float)xl[row * 2048 + d];
        const float u   = dtv * xv;
        sumdt += dtv;
#pragma unroll
        for (int n = 0; n < 16; ++n) {
            const float dA = __expf(dtv * a[n]);
            S[n] = fmaf(S[n], dA, u * Bs[i][n]);
        }
    }

    const size_t base = ((((size_t)b * NC + c) * 2048) + d) * 16;
#pragma unroll
    for (int k = 0; k < 4; ++k) {
        *(float4*)&Sbuf[base + k * 4] =
            make_float4(S[k*4], S[k*4+1], S[k*4+2], S[k*4+3]);
        *(float4*)&Pbuf[base + k * 4] =
            make_float4(__expf(sumdt * a[k*4]),   __expf(sumdt * a[k*4+1]),
                        __expf(sumdt * a[k*4+2]), __expf(sumdt * a[k*4+3]));
    }
}

// ---------------------------------------------------------------------------
// Pass 2: sequential prefix over chunks.
// ---------------------------------------------------------------------------
__global__ __launch_bounds__(256) void scan_chunk_prefix(
    float* __restrict__ Sbuf, const float* __restrict__ Pbuf)
{
    const int tid = blockIdx.x * 256 + threadIdx.x;
    const int b  = tid >> 15;
    const int dn = tid & 32767;

    float H = 0.f;
    for (int c = 0; c < NC; ++c) {
        const size_t idx = ((size_t)b * NC + c) * 32768 + dn;
        const float S = Sbuf[idx];
        const float P = Pbuf[idx];
        Sbuf[idx] = H;
        H = fmaf(P, H, S);
    }
}

// ---------------------------------------------------------------------------
// Scan pass 3: xconv read as bf16 pair; y written as bf16 IN-PLACE over xh
// (same thread reads (row,d) before writing it).
// ---------------------------------------------------------------------------
__global__ __launch_bounds__(256) void scan_final2(
    const bf16_t* __restrict__ xh, const bf16_t* __restrict__ xl,
    const float* __restrict__ dt,
    const float* __restrict__ xdbl,  const float* __restrict__ A_log,
    const float* __restrict__ Dp,    const float* __restrict__ z,
    const float* __restrict__ Hbuf,  bf16_t* __restrict__ y)
{
    __shared__ float BCs[CH][32];

    const int d = blockIdx.x * 256 + threadIdx.x;
    const int c = blockIdx.y;
    const int b = blockIdx.z;
    const long long rowBase = (long long)b * 4096 + (long long)c * CH;

#pragma unroll
    for (int k = 0; k < 4; ++k) {
        const int e = k * 256 + threadIdx.x;
        const int i = e >> 3, j = (e & 7) << 2;
        *(float4*)&BCs[i][j] = *(const float4*)&xdbl[(rowBase + i) * 96 + 64 + j];
    }
    __syncthreads();

    float a[16], h[16];
    const size_t hbase = ((((size_t)b * NC + c) * 2048) + d) * 16;
#pragma unroll
    for (int k = 0; k < 4; ++k) {
        const float4 hv = *(const float4*)&Hbuf[hbase + k * 4];
        h[k*4] = hv.x; h[k*4+1] = hv.y; h[k*4+2] = hv.z; h[k*4+3] = hv.w;
    }
#pragma unroll
    for (int n = 0; n < 16; ++n) a[n] = -__expf(A_log[d * 16 + n]);
    const float Dv = Dp[d];

    for (int i = 0; i < CH; ++i) {
        const long long row = rowBase + i;
        const float dtv = dt[row * 2048 + d];
        const float xv  = (float)xh[row * 2048 + d] + (float)xl[row * 2048 + d];
        const float u   = dtv * xv;
        float acc = 0.f;
#pragma unroll
        for (int n = 0; n < 16; ++n) {
            const float dA = __expf(dtv * a[n]);
            h[n] = fmaf(h[n], dA, u * BCs[i][n]);
            acc  = fmaf(h[n], BCs[i][16 + n], acc);
        }
        const float zv = z[row * 2048 + d];
        float yv = acc + xv * Dv;
        yv = yv * (zv / (1.f + __expf(-zv)));
        y[row * 2048 + d] = (bf16_t)yv;
    }
}

// ---------------------------------------------------------------------------
extern "C" void kernel_launch(void* const* d_in, const int* in_sizes, int n_in,
                              void* d_out, int out_size, void* d_ws, size_t ws_size,
                              hipStream_t stream)
{
    const float* hidden     = (const float*)d_in[0];
    const float* in_proj_w  = (const float*)d_in[1];
    const float* conv_w     = (const float*)d_in[2];
    const float* conv_b     = (const float*)d_in[3];
    const float* x_proj_w   = (const float*)d_in[4];
    const float* dt_proj_w  = (const float*)d_in[5];
    const float* dt_proj_b  = (const float*)d_in[6];
    const float* A_log      = (const float*)d_in[7];
    const float* Dvec       = (const float*)d_in[8];
    const float* out_proj_w = (const float*)d_in[9];
    float* out = (float*)d_out;

    const int L = 4096, dinner = 2048, dmodel = 1024;
    const int M = 2 * L;  // 8192

    // ---- workspace layout: EXACTLY R2's proven 221.25 MB footprint ----
    float* z     = (float*)d_ws;                       // M*2048 fp32
    float* xraw  = z     + (size_t)M * dinner;         // M*2048 (x, xp parts, dt)
    float* xconv = xraw  + (size_t)M * dinner;         // M*2048 (hid, xc pair, y)
    float* xdbl  = xconv + (size_t)M * dinner;         // M*96
    float* Sbuf  = xdbl  + (size_t)M * 96;             // 2*NC*2048*16
    float* Pbuf  = Sbuf  + (size_t)2 * NC * dinner * 16;

    // lifetime-disjoint aliases (timeline):
    //  t0..in_proj : w1 pair = [Sbuf..Pbuf end); hid_h in xconv region
    //  post-in_proj: Sbuf region reused: dth/dtl (2MB, written at add8_split),
    //                wd pair (+2MB), xpw pair (+2.5MB) -- all consumed before
    //                scan_local2 writes Sbuf/Pbuf.
    //  xconv region: hid_h -> xc_h|xc_l (conv out) -> y bf16 over xc_h.
    bf16_t* w1_h  = (bf16_t*)Sbuf;
    bf16_t* w1_l  = w1_h + (size_t)2 * dinner * dmodel;
    bf16_t* hid_h = (bf16_t*)xconv;
    bf16_t* xc_h  = (bf16_t*)xconv;                    // [M][2048] bf16
    bf16_t* xc_l  = xc_h + (size_t)M * dinner;
    float*  xp_part = xraw;
    bf16_t* dth  = (bf16_t*)Sbuf;                      // [M][64] pair = 2 MB
    bf16_t* dtl  = dth + (size_t)M * 64;
    bf16_t* wdh  = dtl + (size_t)M * 64;               // [2048][64] pair
    bf16_t* wdl  = wdh + (size_t)dinner * 64;
    bf16_t* xpwh = wdl + (size_t)dinner * 64;          // [96][2048] pair
    bf16_t* xpwl = xpwh + (size_t)96 * dinner;
    bf16_t* w2_h = (bf16_t*)z;                         // split after scan used z
    bf16_t* w2_l = w2_h + (size_t)dmodel * dinner;

    // ---- 0. t=0 splits: hidden (hi only) + in_proj_w (pair) ----
    const int n4a = M * dmodel / 4;
    const int n4b = 2 * dinner * dmodel / 4;
    split2m<<<(n4a + n4b + 255) / 256, 256, 0, stream>>>(
        hidden, hid_h, n4a,
        in_proj_w, w1_h, w1_l, n4b);

    // ---- 1. in_proj fused (x-half 2-term | z-half 1-term) ----
    in_proj_fused<<<dim3(M / 128, 32), 256, 0, stream>>>(
        hid_h, w1_h, w1_l, xraw, z, dmodel);

    // ---- 1b. split dt_proj_w + x_proj_w (w1 now dead) ----
    const int n4c = dinner * 64 / 4;
    const int n4d = 96 * dinner / 4;
    split2w<<<(n4c + n4d + 255) / 256, 256, 0, stream>>>(
        dt_proj_w, wdh, wdl, n4c,
        x_proj_w, xpwh, xpwl, n4d);

    // ---- 2. conv + bias + SiLU -> bf16 pair ----
    conv_silu4b<<<(M * (long long)dinner / 4) / 256, 256, 0, stream>>>(
        xraw, conv_w, conv_b, xc_h, xc_l, L, dinner);

    // ---- 3. x_proj (3-term MFMA, split-K=8) -> partials -> xdbl + dt pair ----
    gemm_mfma3x<<<dim3(M / 128, 1, 8), 256, 0, stream>>>(
        xc_h, xc_l, xpwh, xpwl, xp_part, dinner, dinner / 8, (size_t)M * 96);
    add8_split<<<(M * 96 / 4 + 255) / 256, 256, 0, stream>>>(
        xp_part, xdbl, dth, dtl, M * 96 / 4, (size_t)M * 96 / 4);

    // ---- 4. dt_proj (3-term MFMA, K=64) -> dt (xraw) ----
    gemm_mfma3p<2><<<dim3(M / 128, 2048 / 128), 256, 0, stream>>>(
        dth, dtl, wdh, wdl, xraw, dt_proj_b, 64, 2048);

    // ---- 5. chunked selective scan ----
    scan_local2<<<dim3(dinner / 256, NC, 2), 256, 0, stream>>>(
        xc_h, xc_l, xraw, xdbl, A_log, Sbuf, Pbuf);
    scan_chunk_prefix<<<256, 256, 0, stream>>>(Sbuf, Pbuf);
    scan_final2<<<dim3(dinner / 256, NC, 2), 256, 0, stream>>>(
        xc_h, xc_l, xraw, xdbl, A_log, Dvec, z, Sbuf, xc_h);

    // ---- 5b. split out_proj_w (z now dead) ----
    split_hl<<<(dmodel * dinner / 4 + 255) / 256, 256, 0, stream>>>(
        out_proj_w, w2_h, w2_l, dmodel * dinner / 4);

    // ---- 6. out_proj (2-term, pure bf16 staging): A = y bf16 -> out ----
    gemm_mfma2ob<<<dim3(M / 64, 1024 / 128), 256, 0, stream>>>(
        xc_h, w2_h, w2_l, out, dinner, 1024);
}